// Round 5
// baseline (833.887 us; speedup 1.0000x reference)
//
#include <hip/hip_runtime.h>
#include <stdint.h>

// ---------------------------------------------------------------------------
// CausalVAELayer forward, MI355X (gfx950). FP32 in / FP32 out (per reference
// dtypes; the harness passes float32 buffers). Internally: bf16 MFMA GEMMs
// (no fp32-input MFMA on CDNA4), fp32 accumulation, bf16 intermediates.
// B=8,S=2048,D=1024,C=16,CD=64,L=1024. Tokens N=16384.
// Output: x_recon [16777216] f32 + total/kl/recon/dag losses (4 f32).
// dag strictly-lower-triangular => nilpotent => trace(expm(dag)) == 16 exactly.
//
// Buffers: S (ws, 32 MiB) = [16384x1024] bf16. d_out doubles as bf16 scratch
// (Obf) until the final GEMM writes fp32 x_recon over it.
// Chain: mu_pre->Obf, lv_pre->S ; kl+causal in-place on Obf ;
//        t->S ; ln_cd S ; z_t->Obf ; d->S ; ln S ; x_recon(f32)->d_out.
// ---------------------------------------------------------------------------

#define NTOK   16384
#define DIM    1024
#define NC     16
#define CD     64
#define NOUT_ELEMS 16777216  // NTOK*DIM

typedef float f32x4 __attribute__((ext_vector_type(4)));
typedef __bf16 bf16x8 __attribute__((ext_vector_type(8)));

__device__ float g_scal[3];   // [0]=kl_acc, [1]=recon_acc, [2]=dag_loss

__device__ __forceinline__ float b2f(uint16_t u) {
  union { uint32_t i; float f; } v; v.i = ((uint32_t)u) << 16; return v.f;
}
__device__ __forceinline__ uint16_t f2b(float f) {
  union { float f; uint32_t i; } v; v.f = f;
  uint32_t x = v.i;
  return (uint16_t)((x + 0x7fffu + ((x >> 16) & 1u)) >> 16);  // RNE
}

// load 8 contiguous elements as bf16x8 (fp32 source converts on the fly)
__device__ __forceinline__ bf16x8 ld8(const uint16_t* p) {
  return *(const bf16x8*)p;
}
__device__ __forceinline__ bf16x8 ld8(const float* p) {
  const f32x4 a = *(const f32x4*)p;
  const f32x4 b = *(const f32x4*)(p + 4);
  bf16x8 r;
  r[0] = (__bf16)a[0]; r[1] = (__bf16)a[1]; r[2] = (__bf16)a[2]; r[3] = (__bf16)a[3];
  r[4] = (__bf16)b[0]; r[5] = (__bf16)b[1]; r[6] = (__bf16)b[2]; r[7] = (__bf16)b[3];
  return r;
}

// ---------------------------------------------------------------------------
// GEMM: C[m,n] = sum_k A[m,k]*W[n,k] + bias[n]
// A: fp32 or bf16(uint16_t). W,bias: fp32. C: bf16(uint16_t) or fp32.
// bf16 MFMA 16x16x32, fp32 acc. blockIdx.z (cz) shifts by cs* for the
// per-concept block-diagonal GEMMs. 256 thr = 4 waves, WMxWN wave grid.
// ---------------------------------------------------------------------------
template<int BM, int BN, int BK, int WM, int WN, typename TA, typename TC>
__global__ __launch_bounds__(256) void gemm_bt_kernel(
    const TA* __restrict__ A, const float* __restrict__ Wm,
    const float* __restrict__ bias, TC* __restrict__ Cq,
    int K, int lda, int ldw, int ldc,
    int csA, int csW, int csB, int csC)
{
  static_assert(WM * WN == 4, "4 waves");
  constexpr int MI = BM / (WM * 16);
  constexpr int NI = BN / (WN * 16);
  constexpr int AI = (BM * BK) / 2048;   // 256 thr x 8 elems per issue
  constexpr int WI = (BN * BK) / 2048;
  constexpr int RPI = 2048 / BK;         // tile rows per issue
  static_assert((BM * BK) % 2048 == 0 && (BN * BK) % 2048 == 0, "");

  __shared__ __align__(16) uint16_t As[BM * BK];
  __shared__ __align__(16) uint16_t Ws[BN * BK];

  const int cz = blockIdx.z;
  A    += (size_t)cz * csA;
  Wm   += (size_t)cz * csW;
  bias += cz * csB;
  Cq   += (size_t)cz * csC;

  const int tid  = threadIdx.x;
  const int wave = tid >> 6;
  const int lane = tid & 63;
  const int q    = lane >> 4;
  const int r16  = lane & 15;
  const int wm   = wave / WN;
  const int wn   = wave % WN;

  const int bm = blockIdx.x * BM;
  const int bn = blockIdx.y * BN;

  const int srow = (tid * 8) / BK;       // row within one staging issue
  const int scol = (tid * 8) % BK;       // col (element) within tile row

  f32x4 acc[MI][NI] = {};

  for (int k0 = 0; k0 < K; k0 += BK) {
    bf16x8 ta[AI], tw[WI];
#pragma unroll
    for (int i = 0; i < AI; ++i)
      ta[i] = ld8(A + (size_t)(bm + i * RPI + srow) * lda + k0 + scol);
#pragma unroll
    for (int i = 0; i < WI; ++i)
      tw[i] = ld8(Wm + (size_t)(bn + i * RPI + srow) * ldw + k0 + scol);

    __syncthreads();   // previous iter's LDS reads done before overwrite
#pragma unroll
    for (int i = 0; i < AI; ++i)
      *(bf16x8*)(As + i * 2048 + tid * 8) = ta[i];
#pragma unroll
    for (int i = 0; i < WI; ++i)
      *(bf16x8*)(Ws + i * 2048 + tid * 8) = tw[i];
    __syncthreads();

    bf16x8 af[MI], wf[NI];
#pragma unroll
    for (int mi = 0; mi < MI; ++mi) {
      const int row = wm * (MI * 16) + mi * 16 + r16;
      af[mi] = *(const bf16x8*)(As + row * BK + q * 8);
    }
#pragma unroll
    for (int ni = 0; ni < NI; ++ni) {
      const int col = wn * (NI * 16) + ni * 16 + r16;
      wf[ni] = *(const bf16x8*)(Ws + col * BK + q * 8);
    }
#pragma unroll
    for (int mi = 0; mi < MI; ++mi)
#pragma unroll
      for (int ni = 0; ni < NI; ++ni)
        acc[mi][ni] = __builtin_amdgcn_mfma_f32_16x16x32_bf16(
            af[mi], wf[ni], acc[mi][ni], 0, 0, 0);
  }

  // Epilogue. C/D layout (m89/m91 verified): col = lane&15, row = (lane>>4)*4+reg.
#pragma unroll
  for (int ni = 0; ni < NI; ++ni) {
    const int col = bn + wn * (NI * 16) + ni * 16 + r16;
    const float bv = bias[col];
#pragma unroll
    for (int mi = 0; mi < MI; ++mi) {
      const int rbase = bm + wm * (MI * 16) + mi * 16 + q * 4;
#pragma unroll
      for (int r = 0; r < 4; ++r) {
        const float v = acc[mi][ni][r] + bv;
        if constexpr (sizeof(TC) == 2)
          Cq[(size_t)(rbase + r) * ldc + col] = f2b(v);
        else
          Cq[(size_t)(rbase + r) * ldc + col] = v;
      }
    }
  }
}

// ---------------------------------------------------------------------------
// Fused: encoder LN (stats over the 2048-wide [mu|lv] row) + KL accumulation
// + causal transform. One block (256 thr) per token.
//   lv = logvar_pre row [1024] bf16 (read, from S)
//   mu = mu_pre row [1024] bf16 (read) -> overwritten with z_causal (in Obf)
// ---------------------------------------------------------------------------
__global__ __launch_bounds__(256) void kl_causal_kernel(
    const uint16_t* __restrict__ lv, uint16_t* __restrict__ mu,
    const float* __restrict__ g, const float* __restrict__ b,
    const float* __restrict__ dag_w)
{
  __shared__ float zsh[1024];
  __shared__ float dg[256];
  __shared__ float red[8];
  __shared__ float red2[4];
  const int tid = threadIdx.x;
  const int tok = blockIdx.x;

  {  // dag matrix: tril(softplus(dag_w), -1)
    const int di = tid >> 4, dj = tid & 15;
    dg[tid] = (dj < di) ? log1pf(expf(dag_w[tid])) : 0.f;
  }

  const uint16_t* lvp = lv + (size_t)tok * 1024;
  uint16_t*       mup = mu + (size_t)tok * 1024;

  float xm[4], xl[4];
  float s1 = 0.f, s2 = 0.f;
#pragma unroll
  for (int e = 0; e < 4; ++e) {
    const int j = tid + e * 256;
    xm[e] = b2f(mup[j]);
    xl[e] = b2f(lvp[j]);
    s1 += xm[e] + xl[e];
    s2 += xm[e] * xm[e] + xl[e] * xl[e];
  }
#pragma unroll
  for (int m = 1; m < 64; m <<= 1) {
    s1 += __shfl_xor(s1, m);
    s2 += __shfl_xor(s2, m);
  }
  const int wave = tid >> 6, lane = tid & 63;
  if (lane == 0) { red[wave] = s1; red[4 + wave] = s2; }
  __syncthreads();
  s1 = red[0] + red[1] + red[2] + red[3];
  s2 = red[4] + red[5] + red[6] + red[7];
  const float mean = s1 * (1.f / 2048.f);
  const float var  = s2 * (1.f / 2048.f) - mean * mean;
  const float rs   = rsqrtf(var + 1e-5f);

  float kl = 0.f;
#pragma unroll
  for (int e = 0; e < 4; ++e) {
    const int j = tid + e * 256;
    const float z = (xm[e] - mean) * rs * g[j] + b[j];
    const float y = (xl[e] - mean) * rs * g[1024 + j] + b[1024 + j];
    zsh[j] = z;
    kl += 1.f + y - z * z - expf(y);
  }
#pragma unroll
  for (int m = 1; m < 64; m <<= 1) kl += __shfl_xor(kl, m);
  if (lane == 0) red2[wave] = kl;
  __syncthreads();  // covers zsh, dg, red2
  if (tid == 0) atomicAdd(&g_scal[0], red2[0] + red2[1] + red2[2] + red2[3]);

  // causal: out[i*64+d] = z[i*64+d] + sum_{j<i} dag[i][j] * z[j*64+d]
  const int d  = tid & 63;
  const int i0 = (tid >> 6) * 4;
#pragma unroll
  for (int ii = 0; ii < 4; ++ii) {
    const int i = i0 + ii;
    float s = zsh[i * 64 + d];
    for (int j = 0; j < i; ++j) s += dg[i * 16 + j] * zsh[j * 64 + d];
    mup[i * 64 + d] = f2b(s);
  }
}

// ---------------------------------------------------------------------------
// LayerNorm(1024) + ReLU, in-place on bf16 rows, one block (256 thr) per row.
// ---------------------------------------------------------------------------
__global__ __launch_bounds__(256) void ln_relu_kernel(
    uint16_t* __restrict__ data, const float* __restrict__ g,
    const float* __restrict__ b)
{
  const int tid = threadIdx.x;
  uint16_t* p = data + (size_t)blockIdx.x * 1024;

  float x[4];
  float s1 = 0.f, s2 = 0.f;
#pragma unroll
  for (int e = 0; e < 4; ++e) {
    x[e] = b2f(p[tid + e * 256]);
    s1 += x[e];
    s2 += x[e] * x[e];
  }
#pragma unroll
  for (int m = 1; m < 64; m <<= 1) {
    s1 += __shfl_xor(s1, m);
    s2 += __shfl_xor(s2, m);
  }
  __shared__ float red[8];
  const int wave = tid >> 6, lane = tid & 63;
  if (lane == 0) { red[wave] = s1; red[4 + wave] = s2; }
  __syncthreads();
  s1 = red[0] + red[1] + red[2] + red[3];
  s2 = red[4] + red[5] + red[6] + red[7];
  const float mean = s1 * (1.f / 1024.f);
  const float var  = s2 * (1.f / 1024.f) - mean * mean;
  const float rs   = rsqrtf(var + 1e-5f);
#pragma unroll
  for (int e = 0; e < 4; ++e) {
    const int j = tid + e * 256;
    const float y = (x[e] - mean) * rs * g[j] + b[j];
    p[j] = f2b(fmaxf(y, 0.f));
  }
}

// ---------------------------------------------------------------------------
// LN(64) + ReLU per (token, concept) group, one wave per group, in-place bf16.
// ---------------------------------------------------------------------------
__global__ __launch_bounds__(256) void ln_cd_kernel(
    uint16_t* __restrict__ t, const float* __restrict__ cg,
    const float* __restrict__ cbt)
{
  const int gidx = blockIdx.x * 4 + (threadIdx.x >> 6);
  const int lane = threadIdx.x & 63;
  const size_t off = (size_t)gidx * 64 + lane;
  const float x = b2f(t[off]);
  float s1 = x, s2 = x * x;
#pragma unroll
  for (int m = 1; m < 64; m <<= 1) {
    s1 += __shfl_xor(s1, m);
    s2 += __shfl_xor(s2, m);
  }
  const float mean = s1 * (1.f / 64.f);
  const float var  = s2 * (1.f / 64.f) - mean * mean;
  const float rs   = rsqrtf(var + 1e-5f);
  const int c = gidx & 15;
  const float y = (x - mean) * rs * cg[c * 64 + lane] + cbt[c * 64 + lane];
  t[off] = f2b(fmaxf(y, 0.f));
}

// ---------------------------------------------------------------------------
// recon partial: sum (x_recon - x)^2 over fp32 arrays, atomicAdd per block.
// ---------------------------------------------------------------------------
__global__ __launch_bounds__(256) void recon_kernel(
    const float* __restrict__ xr, const float* __restrict__ x, int n)
{
  float s = 0.f;
  for (int i = blockIdx.x * 256 + threadIdx.x; i < n; i += gridDim.x * 256) {
    const float d = xr[i] - x[i];
    s += d * d;
  }
#pragma unroll
  for (int m = 1; m < 64; m <<= 1) s += __shfl_xor(s, m);
  __shared__ float red[4];
  const int wave = threadIdx.x >> 6, lane = threadIdx.x & 63;
  if (lane == 0) red[wave] = s;
  __syncthreads();
  if (threadIdx.x == 0) atomicAdd(&g_scal[1], red[0] + red[1] + red[2] + red[3]);
}

// ---------------------------------------------------------------------------
// init: zero kl/recon accumulators; dag_loss = sum(tril softplus) + 16.
// ---------------------------------------------------------------------------
__global__ __launch_bounds__(256) void dag_init_kernel(
    const float* __restrict__ dag_w)
{
  const int t = threadIdx.x;
  const int i = t >> 4, j = t & 15;
  const float v = (j < i) ? log1pf(expf(dag_w[t])) : 0.f;
  float s = v;
#pragma unroll
  for (int m = 1; m < 64; m <<= 1) s += __shfl_xor(s, m);
  __shared__ float red[4];
  const int wave = t >> 6, lane = t & 63;
  if (lane == 0) red[wave] = s;
  __syncthreads();
  if (t == 0) {
    g_scal[0] = 0.f;
    g_scal[1] = 0.f;
    g_scal[2] = red[0] + red[1] + red[2] + red[3] + 16.f;  // trace(expm)=C exactly
  }
}

__global__ __launch_bounds__(64) void finalize_kernel(float* __restrict__ out_tail)
{
  if (threadIdx.x == 0) {
    const float kl    = -0.5f * g_scal[0] * (1.f / (16384.f * 1024.f));
    const float recon = g_scal[1] * (1.f / 16777216.f);
    const float dagl  = g_scal[2];
    out_tail[0] = recon + 0.3f * kl + 1.0f * dagl;
    out_tail[1] = kl;
    out_tail[2] = recon;
    out_tail[3] = dagl;
  }
}

// ---------------------------------------------------------------------------
extern "C" void kernel_launch(void* const* d_in, const int* in_sizes, int n_in,
                              void* d_out, int out_size, void* d_ws, size_t ws_size,
                              hipStream_t stream) {
  const float* x      = (const float*)d_in[0];
  const float* enc_w  = (const float*)d_in[1];
  const float* enc_b  = (const float*)d_in[2];
  const float* enc_g  = (const float*)d_in[3];
  const float* enc_bt = (const float*)d_in[4];
  const float* dag_w  = (const float*)d_in[5];
  const float* cw1    = (const float*)d_in[6];
  const float* cb1    = (const float*)d_in[7];
  const float* cg     = (const float*)d_in[8];
  const float* cbt    = (const float*)d_in[9];
  const float* cw2    = (const float*)d_in[10];
  const float* cb2    = (const float*)d_in[11];
  const float* dec_w1 = (const float*)d_in[12];
  const float* dec_b1 = (const float*)d_in[13];
  const float* dec_g  = (const float*)d_in[14];
  const float* dec_bt = (const float*)d_in[15];
  const float* dec_w2 = (const float*)d_in[16];
  const float* dec_b2 = (const float*)d_in[17];

  uint16_t* S   = (uint16_t*)d_ws;    // [16384 x 1024] bf16 = 32 MiB
  uint16_t* Obf = (uint16_t*)d_out;   // bf16 scratch inside d_out (dies at step 9)
  float*    O   = (float*)d_out;      // final fp32 x_recon + losses

  // 1. accumulator init + dag_loss
  dag_init_kernel<<<1, 256, 0, stream>>>(dag_w);

  // 2a. mu_pre = x @ enc_w[0:1024]^T + enc_b[0:1024] -> Obf
  gemm_bt_kernel<128, 128, 32, 2, 2, float, uint16_t>
      <<<dim3(128, 8, 1), 256, 0, stream>>>(
      x, enc_w, enc_b, Obf, DIM, DIM, DIM, DIM, 0, 0, 0, 0);

  // 2b. lv_pre = x @ enc_w[1024:2048]^T + enc_b[1024:2048] -> S
  gemm_bt_kernel<128, 128, 32, 2, 2, float, uint16_t>
      <<<dim3(128, 8, 1), 256, 0, stream>>>(
      x, enc_w + (size_t)DIM * DIM, enc_b + DIM, S, DIM, DIM, DIM, DIM,
      0, 0, 0, 0);

  // 3. fused LN + KL + causal: z_causal overwrites mu in Obf
  kl_causal_kernel<<<NTOK, 256, 0, stream>>>(S, Obf, enc_g, enc_bt, dag_w);

  // 4. concept linear 1 (block-diag): t = z_causal @ cw1^T + cb1 -> S
  gemm_bt_kernel<128, 64, 32, 4, 1, uint16_t, uint16_t>
      <<<dim3(128, 1, 16), 256, 0, stream>>>(
      Obf, cw1, cb1, S, CD, DIM, CD, DIM, 64, 4096, 64, 64);

  // 5. per-concept LN(64) + ReLU (in-place on S)
  ln_cd_kernel<<<NTOK * NC / 4, 256, 0, stream>>>(S, cg, cbt);

  // 6. concept linear 2: z_t = t @ cw2^T + cb2 -> Obf
  gemm_bt_kernel<128, 64, 32, 4, 1, uint16_t, uint16_t>
      <<<dim3(128, 1, 16), 256, 0, stream>>>(
      S, cw2, cb2, Obf, CD, DIM, CD, DIM, 64, 4096, 64, 64);

  // 7. decoder GEMM1: d_pre = z_t @ dec_w1^T + dec_b1 -> S
  gemm_bt_kernel<128, 128, 32, 2, 2, uint16_t, uint16_t>
      <<<dim3(128, 8, 1), 256, 0, stream>>>(
      Obf, dec_w1, dec_b1, S, DIM, DIM, DIM, DIM, 0, 0, 0, 0);

  // 8. decoder LN + ReLU (in-place on S)
  ln_relu_kernel<<<NTOK, 256, 0, stream>>>(S, dec_g, dec_bt);

  // 9. decoder GEMM2: x_recon = d @ dec_w2^T + dec_b2 -> O (fp32, overwrites Obf)
  gemm_bt_kernel<128, 128, 32, 2, 2, uint16_t, float>
      <<<dim3(128, 8, 1), 256, 0, stream>>>(
      S, dec_w2, dec_b2, O, DIM, DIM, DIM, DIM, 0, 0, 0, 0);

  // 10. recon loss partials (fp32 vs fp32)
  recon_kernel<<<4096, 256, 0, stream>>>(O, x, NOUT_ELEMS);

  // 11. final scalars
  finalize_kernel<<<1, 64, 0, stream>>>(O + (size_t)NOUT_ELEMS);
}

// Round 6
// 603.075 us; speedup vs baseline: 1.3827x; 1.3827x over previous
//
#include <hip/hip_runtime.h>
#include <stdint.h>

// ---------------------------------------------------------------------------
// CausalVAELayer forward, MI355X (gfx950). FP32 in / FP32 out.
// Internally: bf16 MFMA GEMMs (no fp32-input MFMA on CDNA4), fp32 acc,
// bf16 intermediates. B=8,S=2048,D=1024,C=16,CD=64,L=1024. Tokens N=16384.
// Output: x_recon [16777216] f32 + total/kl/recon/dag losses (4 f32).
// dag strictly-lower-triangular => nilpotent => trace(expm(dag)) == 16 exactly.
//
// ROUND 6: loss atomics spread over 256 slots (single-address atomic
// serialization was 216 us in kl_causal + ~50 us in recon); all elementwise
// kernels vectorized (ushort4/float4). GEMMs unchanged from round 5.
// Buffers: S (ws, 32 MiB) = [16384x1024] bf16; d_out doubles as bf16 scratch.
// ---------------------------------------------------------------------------

#define NTOK   16384
#define DIM    1024
#define NC     16
#define CD     64
#define NOUT_ELEMS 16777216  // NTOK*DIM

typedef float f32x4 __attribute__((ext_vector_type(4)));
typedef __bf16 bf16x8 __attribute__((ext_vector_type(8)));
typedef unsigned short u16x4 __attribute__((ext_vector_type(4)));

__device__ float g_scal[3];    // [2]=dag_loss
__device__ float g_part[512];  // [0..256)=kl partials, [256..512)=recon partials

__device__ __forceinline__ float b2f(uint16_t u) {
  union { uint32_t i; float f; } v; v.i = ((uint32_t)u) << 16; return v.f;
}
__device__ __forceinline__ uint16_t f2b(float f) {
  union { float f; uint32_t i; } v; v.f = f;
  uint32_t x = v.i;
  return (uint16_t)((x + 0x7fffu + ((x >> 16) & 1u)) >> 16);  // RNE
}

// load 8 contiguous elements as bf16x8 (fp32 source converts on the fly)
__device__ __forceinline__ bf16x8 ld8(const uint16_t* p) {
  return *(const bf16x8*)p;
}
__device__ __forceinline__ bf16x8 ld8(const float* p) {
  const f32x4 a = *(const f32x4*)p;
  const f32x4 b = *(const f32x4*)(p + 4);
  bf16x8 r;
  r[0] = (__bf16)a[0]; r[1] = (__bf16)a[1]; r[2] = (__bf16)a[2]; r[3] = (__bf16)a[3];
  r[4] = (__bf16)b[0]; r[5] = (__bf16)b[1]; r[6] = (__bf16)b[2]; r[7] = (__bf16)b[3];
  return r;
}

// ---------------------------------------------------------------------------
// GEMM: C[m,n] = sum_k A[m,k]*W[n,k] + bias[n]
// A: fp32 or bf16(uint16_t). W,bias: fp32. C: bf16(uint16_t) or fp32.
// bf16 MFMA 16x16x32, fp32 acc. blockIdx.z (cz) shifts by cs* for the
// per-concept block-diagonal GEMMs. 256 thr = 4 waves, WMxWN wave grid.
// ---------------------------------------------------------------------------
template<int BM, int BN, int BK, int WM, int WN, typename TA, typename TC>
__global__ __launch_bounds__(256) void gemm_bt_kernel(
    const TA* __restrict__ A, const float* __restrict__ Wm,
    const float* __restrict__ bias, TC* __restrict__ Cq,
    int K, int lda, int ldw, int ldc,
    int csA, int csW, int csB, int csC)
{
  static_assert(WM * WN == 4, "4 waves");
  constexpr int MI = BM / (WM * 16);
  constexpr int NI = BN / (WN * 16);
  constexpr int AI = (BM * BK) / 2048;   // 256 thr x 8 elems per issue
  constexpr int WI = (BN * BK) / 2048;
  constexpr int RPI = 2048 / BK;         // tile rows per issue
  static_assert((BM * BK) % 2048 == 0 && (BN * BK) % 2048 == 0, "");

  __shared__ __align__(16) uint16_t As[BM * BK];
  __shared__ __align__(16) uint16_t Ws[BN * BK];

  const int cz = blockIdx.z;
  A    += (size_t)cz * csA;
  Wm   += (size_t)cz * csW;
  bias += cz * csB;
  Cq   += (size_t)cz * csC;

  const int tid  = threadIdx.x;
  const int wave = tid >> 6;
  const int lane = tid & 63;
  const int q    = lane >> 4;
  const int r16  = lane & 15;
  const int wm   = wave / WN;
  const int wn   = wave % WN;

  const int bm = blockIdx.x * BM;
  const int bn = blockIdx.y * BN;

  const int srow = (tid * 8) / BK;       // row within one staging issue
  const int scol = (tid * 8) % BK;       // col (element) within tile row

  f32x4 acc[MI][NI] = {};

  for (int k0 = 0; k0 < K; k0 += BK) {
    bf16x8 ta[AI], tw[WI];
#pragma unroll
    for (int i = 0; i < AI; ++i)
      ta[i] = ld8(A + (size_t)(bm + i * RPI + srow) * lda + k0 + scol);
#pragma unroll
    for (int i = 0; i < WI; ++i)
      tw[i] = ld8(Wm + (size_t)(bn + i * RPI + srow) * ldw + k0 + scol);

    __syncthreads();   // previous iter's LDS reads done before overwrite
#pragma unroll
    for (int i = 0; i < AI; ++i)
      *(bf16x8*)(As + i * 2048 + tid * 8) = ta[i];
#pragma unroll
    for (int i = 0; i < WI; ++i)
      *(bf16x8*)(Ws + i * 2048 + tid * 8) = tw[i];
    __syncthreads();

    bf16x8 af[MI], wf[NI];
#pragma unroll
    for (int mi = 0; mi < MI; ++mi) {
      const int row = wm * (MI * 16) + mi * 16 + r16;
      af[mi] = *(const bf16x8*)(As + row * BK + q * 8);
    }
#pragma unroll
    for (int ni = 0; ni < NI; ++ni) {
      const int col = wn * (NI * 16) + ni * 16 + r16;
      wf[ni] = *(const bf16x8*)(Ws + col * BK + q * 8);
    }
#pragma unroll
    for (int mi = 0; mi < MI; ++mi)
#pragma unroll
      for (int ni = 0; ni < NI; ++ni)
        acc[mi][ni] = __builtin_amdgcn_mfma_f32_16x16x32_bf16(
            af[mi], wf[ni], acc[mi][ni], 0, 0, 0);
  }

  // Epilogue. C/D layout (m89/m91 verified): col = lane&15, row = (lane>>4)*4+reg.
#pragma unroll
  for (int ni = 0; ni < NI; ++ni) {
    const int col = bn + wn * (NI * 16) + ni * 16 + r16;
    const float bv = bias[col];
#pragma unroll
    for (int mi = 0; mi < MI; ++mi) {
      const int rbase = bm + wm * (MI * 16) + mi * 16 + q * 4;
#pragma unroll
      for (int r = 0; r < 4; ++r) {
        const float v = acc[mi][ni][r] + bv;
        if constexpr (sizeof(TC) == 2)
          Cq[(size_t)(rbase + r) * ldc + col] = f2b(v);
        else
          Cq[(size_t)(rbase + r) * ldc + col] = v;
      }
    }
  }
}

// ---------------------------------------------------------------------------
// Fused: encoder LN (stats over the 2048-wide [mu|lv] row) + KL partials
// (spread atomics) + causal transform. One block (256 thr) per token.
// Vectorized: ushort4 loads/stores, f32x4 LDS traffic.
// ---------------------------------------------------------------------------
__global__ __launch_bounds__(256) void kl_causal_kernel(
    const uint16_t* __restrict__ lv, uint16_t* __restrict__ mu,
    const float* __restrict__ g, const float* __restrict__ b,
    const float* __restrict__ dag_w)
{
  __shared__ __align__(16) float zsh[1024];
  __shared__ float dg[256];
  __shared__ float red[8];
  __shared__ float red2[4];
  const int tid = threadIdx.x;
  const int tok = blockIdx.x;
  const int e0  = tid * 4;

  {  // dag matrix: tril(softplus(dag_w), -1)
    const int di = tid >> 4, dj = tid & 15;
    dg[tid] = (dj < di) ? log1pf(expf(dag_w[tid])) : 0.f;
  }

  const uint16_t* lvp = lv + (size_t)tok * 1024;
  uint16_t*       mup = mu + (size_t)tok * 1024;

  const u16x4 m4 = *(const u16x4*)(mup + e0);
  const u16x4 l4 = *(const u16x4*)(lvp + e0);
  float xm[4], xl[4];
  float s1 = 0.f, s2 = 0.f;
#pragma unroll
  for (int k = 0; k < 4; ++k) {
    xm[k] = b2f(m4[k]);
    xl[k] = b2f(l4[k]);
    s1 += xm[k] + xl[k];
    s2 += xm[k] * xm[k] + xl[k] * xl[k];
  }
#pragma unroll
  for (int m = 1; m < 64; m <<= 1) {
    s1 += __shfl_xor(s1, m);
    s2 += __shfl_xor(s2, m);
  }
  const int wave = tid >> 6, lane = tid & 63;
  if (lane == 0) { red[wave] = s1; red[4 + wave] = s2; }
  __syncthreads();
  s1 = red[0] + red[1] + red[2] + red[3];
  s2 = red[4] + red[5] + red[6] + red[7];
  const float mean = s1 * (1.f / 2048.f);
  const float var  = s2 * (1.f / 2048.f) - mean * mean;
  const float rs   = rsqrtf(var + 1e-5f);

  const f32x4 g4m = *(const f32x4*)(g + e0);
  const f32x4 b4m = *(const f32x4*)(b + e0);
  const f32x4 g4l = *(const f32x4*)(g + 1024 + e0);
  const f32x4 b4l = *(const f32x4*)(b + 1024 + e0);
  float kl = 0.f;
  f32x4 z;
#pragma unroll
  for (int k = 0; k < 4; ++k) {
    z[k] = (xm[k] - mean) * rs * g4m[k] + b4m[k];
    const float y = (xl[k] - mean) * rs * g4l[k] + b4l[k];
    kl += 1.f + y - z[k] * z[k] - expf(y);
  }
  *(f32x4*)(zsh + e0) = z;
#pragma unroll
  for (int m = 1; m < 64; m <<= 1) kl += __shfl_xor(kl, m);
  if (lane == 0) red2[wave] = kl;
  __syncthreads();  // covers zsh, dg, red2
  if (tid == 0)
    atomicAdd(&g_part[tok & 255], red2[0] + red2[1] + red2[2] + red2[3]);

  // causal: thread covers elems [e0, e0+4) -> concept i = e0>>6, dims d0..d0+3
  const int i  = e0 >> 6;
  const int d0 = e0 & 63;
  f32x4 s = *(const f32x4*)(zsh + e0);
  for (int j = 0; j < i; ++j) {
    const float w = dg[i * 16 + j];
    const f32x4 zj = *(const f32x4*)(zsh + j * 64 + d0);
    s[0] += w * zj[0]; s[1] += w * zj[1]; s[2] += w * zj[2]; s[3] += w * zj[3];
  }
  u16x4 o;
#pragma unroll
  for (int k = 0; k < 4; ++k) o[k] = f2b(s[k]);
  *(u16x4*)(mup + e0) = o;
}

// ---------------------------------------------------------------------------
// LayerNorm(1024) + ReLU, in-place on bf16 rows, one block (256 thr) per row.
// Vectorized ushort4 / float4.
// ---------------------------------------------------------------------------
__global__ __launch_bounds__(256) void ln_relu_kernel(
    uint16_t* __restrict__ data, const float* __restrict__ g,
    const float* __restrict__ b)
{
  const int tid = threadIdx.x;
  const int e0  = tid * 4;
  uint16_t* p = data + (size_t)blockIdx.x * 1024;

  const u16x4 v4 = *(const u16x4*)(p + e0);
  float x[4];
  float s1 = 0.f, s2 = 0.f;
#pragma unroll
  for (int k = 0; k < 4; ++k) {
    x[k] = b2f(v4[k]);
    s1 += x[k];
    s2 += x[k] * x[k];
  }
#pragma unroll
  for (int m = 1; m < 64; m <<= 1) {
    s1 += __shfl_xor(s1, m);
    s2 += __shfl_xor(s2, m);
  }
  __shared__ float red[8];
  const int wave = tid >> 6, lane = tid & 63;
  if (lane == 0) { red[wave] = s1; red[4 + wave] = s2; }
  __syncthreads();
  s1 = red[0] + red[1] + red[2] + red[3];
  s2 = red[4] + red[5] + red[6] + red[7];
  const float mean = s1 * (1.f / 1024.f);
  const float var  = s2 * (1.f / 1024.f) - mean * mean;
  const float rs   = rsqrtf(var + 1e-5f);

  const f32x4 g4 = *(const f32x4*)(g + e0);
  const f32x4 b4 = *(const f32x4*)(b + e0);
  u16x4 o;
#pragma unroll
  for (int k = 0; k < 4; ++k) {
    const float y = (x[k] - mean) * rs * g4[k] + b4[k];
    o[k] = f2b(fmaxf(y, 0.f));
  }
  *(u16x4*)(p + e0) = o;
}

// ---------------------------------------------------------------------------
// LN(64) + ReLU per (token, concept) group. 16 groups per block; each group
// handled by a 16-lane chunk (4 elems/lane, ushort4). In-place bf16.
// ---------------------------------------------------------------------------
__global__ __launch_bounds__(256) void ln_cd_kernel(
    uint16_t* __restrict__ t, const float* __restrict__ cg,
    const float* __restrict__ cbt)
{
  const int tid = threadIdx.x;
  const int sub = tid >> 4;    // group within block (0..15)
  const int le  = tid & 15;    // 16-lane chunk position
  const int gidx = blockIdx.x * 16 + sub;
  const int c = gidx & 15;
  const size_t off = (size_t)gidx * 64 + le * 4;

  const u16x4 v4 = *(const u16x4*)(t + off);
  float x[4];
  float s1 = 0.f, s2 = 0.f;
#pragma unroll
  for (int k = 0; k < 4; ++k) {
    x[k] = b2f(v4[k]);
    s1 += x[k];
    s2 += x[k] * x[k];
  }
#pragma unroll
  for (int m = 1; m < 16; m <<= 1) {  // reduce within the 16-lane chunk
    s1 += __shfl_xor(s1, m);
    s2 += __shfl_xor(s2, m);
  }
  const float mean = s1 * (1.f / 64.f);
  const float var  = s2 * (1.f / 64.f) - mean * mean;
  const float rs   = rsqrtf(var + 1e-5f);

  const f32x4 cg4  = *(const f32x4*)(cg + c * 64 + le * 4);
  const f32x4 cbt4 = *(const f32x4*)(cbt + c * 64 + le * 4);
  u16x4 o;
#pragma unroll
  for (int k = 0; k < 4; ++k) {
    const float y = (x[k] - mean) * rs * cg4[k] + cbt4[k];
    o[k] = f2b(fmaxf(y, 0.f));
  }
  *(u16x4*)(t + off) = o;
}

// ---------------------------------------------------------------------------
// recon partials: sum (x_recon - x)^2, float4, spread atomics over 256 slots.
// ---------------------------------------------------------------------------
__global__ __launch_bounds__(256) void recon_kernel(
    const float* __restrict__ xr, const float* __restrict__ x, int n4)
{
  const f32x4* xr4 = (const f32x4*)xr;
  const f32x4* x4  = (const f32x4*)x;
  float s = 0.f;
  for (int i = blockIdx.x * 256 + threadIdx.x; i < n4; i += gridDim.x * 256) {
    const f32x4 d = xr4[i] - x4[i];
    s += d[0] * d[0] + d[1] * d[1] + d[2] * d[2] + d[3] * d[3];
  }
#pragma unroll
  for (int m = 1; m < 64; m <<= 1) s += __shfl_xor(s, m);
  __shared__ float red[4];
  const int wave = threadIdx.x >> 6, lane = threadIdx.x & 63;
  if (lane == 0) red[wave] = s;
  __syncthreads();
  if (threadIdx.x == 0)
    atomicAdd(&g_part[256 + (blockIdx.x & 255)], red[0] + red[1] + red[2] + red[3]);
}

// ---------------------------------------------------------------------------
// init: zero 512 partial slots; dag_loss = sum(tril softplus) + 16.
// ---------------------------------------------------------------------------
__global__ __launch_bounds__(256) void dag_init_kernel(
    const float* __restrict__ dag_w)
{
  const int t = threadIdx.x;
  g_part[t] = 0.f;
  g_part[256 + t] = 0.f;
  const int i = t >> 4, j = t & 15;
  const float v = (j < i) ? log1pf(expf(dag_w[t])) : 0.f;
  float s = v;
#pragma unroll
  for (int m = 1; m < 64; m <<= 1) s += __shfl_xor(s, m);
  __shared__ float red[4];
  const int wave = t >> 6, lane = t & 63;
  if (lane == 0) red[wave] = s;
  __syncthreads();
  if (t == 0)
    g_scal[2] = red[0] + red[1] + red[2] + red[3] + 16.f;  // trace(expm)=C exactly
}

// ---------------------------------------------------------------------------
// finalize: sum the 256+256 partial slots, emit the 4 loss scalars.
// ---------------------------------------------------------------------------
__global__ __launch_bounds__(256) void finalize_kernel(float* __restrict__ out_tail)
{
  const int tid = threadIdx.x;
  float kl = g_part[tid];
  float rc = g_part[256 + tid];
#pragma unroll
  for (int m = 1; m < 64; m <<= 1) {
    kl += __shfl_xor(kl, m);
    rc += __shfl_xor(rc, m);
  }
  __shared__ float red[8];
  const int wave = tid >> 6, lane = tid & 63;
  if (lane == 0) { red[wave] = kl; red[4 + wave] = rc; }
  __syncthreads();
  if (tid == 0) {
    const float kls = red[0] + red[1] + red[2] + red[3];
    const float rcs = red[4] + red[5] + red[6] + red[7];
    const float kl_l   = -0.5f * kls * (1.f / (16384.f * 1024.f));
    const float recon  = rcs * (1.f / 16777216.f);
    const float dagl   = g_scal[2];
    out_tail[0] = recon + 0.3f * kl_l + 1.0f * dagl;
    out_tail[1] = kl_l;
    out_tail[2] = recon;
    out_tail[3] = dagl;
  }
}

// ---------------------------------------------------------------------------
extern "C" void kernel_launch(void* const* d_in, const int* in_sizes, int n_in,
                              void* d_out, int out_size, void* d_ws, size_t ws_size,
                              hipStream_t stream) {
  const float* x      = (const float*)d_in[0];
  const float* enc_w  = (const float*)d_in[1];
  const float* enc_b  = (const float*)d_in[2];
  const float* enc_g  = (const float*)d_in[3];
  const float* enc_bt = (const float*)d_in[4];
  const float* dag_w  = (const float*)d_in[5];
  const float* cw1    = (const float*)d_in[6];
  const float* cb1    = (const float*)d_in[7];
  const float* cg     = (const float*)d_in[8];
  const float* cbt    = (const float*)d_in[9];
  const float* cw2    = (const float*)d_in[10];
  const float* cb2    = (const float*)d_in[11];
  const float* dec_w1 = (const float*)d_in[12];
  const float* dec_b1 = (const float*)d_in[13];
  const float* dec_g  = (const float*)d_in[14];
  const float* dec_bt = (const float*)d_in[15];
  const float* dec_w2 = (const float*)d_in[16];
  const float* dec_b2 = (const float*)d_in[17];

  uint16_t* S   = (uint16_t*)d_ws;    // [16384 x 1024] bf16 = 32 MiB
  uint16_t* Obf = (uint16_t*)d_out;   // bf16 scratch inside d_out (dies at step 9)
  float*    O   = (float*)d_out;      // final fp32 x_recon + losses

  // 1. zero partials + dag_loss
  dag_init_kernel<<<1, 256, 0, stream>>>(dag_w);

  // 2a. mu_pre = x @ enc_w[0:1024]^T + enc_b[0:1024] -> Obf
  gemm_bt_kernel<128, 128, 32, 2, 2, float, uint16_t>
      <<<dim3(128, 8, 1), 256, 0, stream>>>(
      x, enc_w, enc_b, Obf, DIM, DIM, DIM, DIM, 0, 0, 0, 0);

  // 2b. lv_pre = x @ enc_w[1024:2048]^T + enc_b[1024:2048] -> S
  gemm_bt_kernel<128, 128, 32, 2, 2, float, uint16_t>
      <<<dim3(128, 8, 1), 256, 0, stream>>>(
      x, enc_w + (size_t)DIM * DIM, enc_b + DIM, S, DIM, DIM, DIM, DIM,
      0, 0, 0, 0);

  // 3. fused LN + KL + causal: z_causal overwrites mu in Obf
  kl_causal_kernel<<<NTOK, 256, 0, stream>>>(S, Obf, enc_g, enc_bt, dag_w);

  // 4. concept linear 1 (block-diag): t = z_causal @ cw1^T + cb1 -> S
  gemm_bt_kernel<128, 64, 32, 4, 1, uint16_t, uint16_t>
      <<<dim3(128, 1, 16), 256, 0, stream>>>(
      Obf, cw1, cb1, S, CD, DIM, CD, DIM, 64, 4096, 64, 64);

  // 5. per-concept LN(64) + ReLU (in-place on S)
  ln_cd_kernel<<<NTOK * NC / 16, 256, 0, stream>>>(S, cg, cbt);

  // 6. concept linear 2: z_t = t @ cw2^T + cb2 -> Obf
  gemm_bt_kernel<128, 64, 32, 4, 1, uint16_t, uint16_t>
      <<<dim3(128, 1, 16), 256, 0, stream>>>(
      S, cw2, cb2, Obf, CD, DIM, CD, DIM, 64, 4096, 64, 64);

  // 7. decoder GEMM1: d_pre = z_t @ dec_w1^T + dec_b1 -> S
  gemm_bt_kernel<128, 128, 32, 2, 2, uint16_t, uint16_t>
      <<<dim3(128, 8, 1), 256, 0, stream>>>(
      Obf, dec_w1, dec_b1, S, DIM, DIM, DIM, DIM, 0, 0, 0, 0);

  // 8. decoder LN + ReLU (in-place on S)
  ln_relu_kernel<<<NTOK, 256, 0, stream>>>(S, dec_g, dec_bt);

  // 9. decoder GEMM2: x_recon = d @ dec_w2^T + dec_b2 -> O (fp32, overwrites Obf)
  gemm_bt_kernel<128, 128, 32, 2, 2, uint16_t, float>
      <<<dim3(128, 8, 1), 256, 0, stream>>>(
      S, dec_w2, dec_b2, O, DIM, DIM, DIM, DIM, 0, 0, 0, 0);

  // 10. recon loss partials (fp32 vs fp32, float4)
  recon_kernel<<<1024, 256, 0, stream>>>(O, x, NOUT_ELEMS / 4);

  // 11. final scalars
  finalize_kernel<<<1, 256, 0, stream>>>(O + (size_t)NOUT_ELEMS);
}

// Round 7
// 504.483 us; speedup vs baseline: 1.6530x; 1.1954x over previous
//
#include <hip/hip_runtime.h>
#include <stdint.h>

// ---------------------------------------------------------------------------
// CausalVAELayer forward, MI355X (gfx950). FP32 in / FP32 out.
// Internally: bf16 MFMA GEMMs, fp32 acc, bf16 intermediates.
// B=8,S=2048,D=1024,C=16,CD=64,L=1024. Tokens N=16384.
// dag strictly-lower-triangular => nilpotent => trace(expm(dag)) == 16 exactly.
//
// ROUND 7: pre-convert x + all weights to bf16 once per launch, then every
// GEMM uses the m97-verified global_load_lds width-16 staging (round-6 GEMMs
// were register-staged and MfmaUtil=13.5%-bound at ~100us each).
// Workspace: S (32 MiB) + Wbf (8.25 MiB) = 40.3 MiB.
// d_out: [0,33.5MB) bf16 scratch Obf; [33.5,67MB) x_bf16 (dead after encoder
// GEMMs); finally fp32 x_recon overwrites everything.
// ---------------------------------------------------------------------------

#define NTOK   16384
#define DIM    1024
#define NC     16
#define CD     64
#define NOUT_ELEMS 16777216  // NTOK*DIM

typedef float f32x4 __attribute__((ext_vector_type(4)));
typedef __bf16 bf16x8 __attribute__((ext_vector_type(8)));
typedef unsigned short u16x4 __attribute__((ext_vector_type(4)));
typedef unsigned short u16x8 __attribute__((ext_vector_type(8)));

__device__ float g_scal[3];    // [2]=dag_loss
__device__ float g_part[512];  // [0..256)=kl partials, [256..512)=recon partials

__device__ __forceinline__ float b2f(uint16_t u) {
  union { uint32_t i; float f; } v; v.i = ((uint32_t)u) << 16; return v.f;
}
__device__ __forceinline__ uint16_t f2b(float f) {
  union { float f; uint32_t i; } v; v.f = f;
  uint32_t x = v.i;
  return (uint16_t)((x + 0x7fffu + ((x >> 16) & 1u)) >> 16);  // RNE
}

__device__ __forceinline__ void gload_lds16(const uint16_t* g, uint16_t* l) {
  __builtin_amdgcn_global_load_lds(
      (const __attribute__((address_space(1))) void*)g,
      (__attribute__((address_space(3))) void*)l, 16, 0, 0);
}

// convert 8 fp32 -> 8 bf16 (RNE), 16B store
__device__ __forceinline__ void cvt8(const float* s, uint16_t* d) {
  const f32x4 a = *(const f32x4*)s;
  const f32x4 b = *(const f32x4*)(s + 4);
  u16x8 o;
  o[0]=f2b(a[0]); o[1]=f2b(a[1]); o[2]=f2b(a[2]); o[3]=f2b(a[3]);
  o[4]=f2b(b[0]); o[5]=f2b(b[1]); o[6]=f2b(b[2]); o[7]=f2b(b[3]);
  *(u16x8*)d = o;
}

__global__ __launch_bounds__(256) void cvt_x_kernel(
    const float* __restrict__ src, uint16_t* __restrict__ dst)
{
  const int i = blockIdx.x * 256 + threadIdx.x;  // elem8 index, grid covers n/8
  cvt8(src + (size_t)i * 8, dst + (size_t)i * 8);
}

// weights, concatenated into Wbf: [enc_w 2M | dec_w1 1M | dec_w2 1M | cw1 64K | cw2 64K]
__global__ __launch_bounds__(256) void cvt_weights_kernel(
    const float* __restrict__ ew, const float* __restrict__ d1,
    const float* __restrict__ d2, const float* __restrict__ c1,
    const float* __restrict__ c2, uint16_t* __restrict__ out)
{
  const int i = blockIdx.x * 256 + threadIdx.x;  // elem8 idx, total 540672
  const float* src; uint16_t* dst; int off;
  if (i < 262144)      { src = ew; dst = out;           off = i; }
  else if (i < 393216) { src = d1; dst = out + 2097152; off = i - 262144; }
  else if (i < 524288) { src = d2; dst = out + 3145728; off = i - 393216; }
  else if (i < 532480) { src = c1; dst = out + 4194304; off = i - 524288; }
  else                 { src = c2; dst = out + 4259840; off = i - 532480; }
  cvt8(src + (size_t)off * 8, dst + (size_t)off * 8);
}

// ---------------------------------------------------------------------------
// GEMM: C[m,n] = sum_k A[m,k]*W[n,k] + bias[n]. A,W bf16; bias fp32; C bf16/f32.
// m97-verified structure: global_load_lds width-16 staging, 2-barrier K-loop.
// blockIdx.z (cz) shifts by cs* for the per-concept block-diagonal GEMMs.
// ---------------------------------------------------------------------------
template<int BM, int BN, int BK, int WM, int WN, typename TC>
__global__ __launch_bounds__(256) void gemm_bt_kernel(
    const uint16_t* __restrict__ A, const uint16_t* __restrict__ Wm,
    const float* __restrict__ bias, TC* __restrict__ Cq,
    int K, int lda, int ldw, int ldc,
    int csA, int csW, int csB, int csC)
{
  static_assert(WM * WN == 4, "4 waves");
  constexpr int MI = BM / (WM * 16);
  constexpr int NI = BN / (WN * 16);
  constexpr int AI = (BM * BK * 2) / 4096;   // global_load_lds issues for A
  constexpr int WI = (BN * BK * 2) / 4096;
  constexpr int RPI = 4096 / (BK * 2);       // tile rows per 4096B issue
  static_assert((BM * BK * 2) % 4096 == 0 && (BN * BK * 2) % 4096 == 0, "");

  __shared__ __align__(16) uint16_t lds[BM * BK + BN * BK];
  uint16_t* As = lds;
  uint16_t* Ws = lds + BM * BK;

  const int cz = blockIdx.z;
  A    += (size_t)cz * csA;
  Wm   += (size_t)cz * csW;
  bias += cz * csB;
  Cq   += (size_t)cz * csC;

  const int tid  = threadIdx.x;
  const int wave = tid >> 6;
  const int lane = tid & 63;
  const int q    = lane >> 4;
  const int r16  = lane & 15;
  const int wm   = wave / WN;
  const int wn   = wave % WN;

  const int bm = blockIdx.x * BM;
  const int bn = blockIdx.y * BN;

  const int srow = (tid * 16) / (BK * 2);        // row within a 4096B issue
  const int scol = ((tid * 16) % (BK * 2)) / 2;  // element col in tile

  f32x4 acc[MI][NI] = {};

  for (int k0 = 0; k0 < K; k0 += BK) {
#pragma unroll
    for (int i = 0; i < AI; ++i) {
      const uint16_t* g = A + (size_t)(bm + i * RPI + srow) * lda + (k0 + scol);
      gload_lds16(g, (uint16_t*)((char*)As + i * 4096 + wave * 1024));
    }
#pragma unroll
    for (int i = 0; i < WI; ++i) {
      const uint16_t* g = Wm + (size_t)(bn + i * RPI + srow) * ldw + (k0 + scol);
      gload_lds16(g, (uint16_t*)((char*)Ws + i * 4096 + wave * 1024));
    }
    __syncthreads();

    bf16x8 af[MI], wf[NI];
#pragma unroll
    for (int mi = 0; mi < MI; ++mi) {
      const int row = wm * (MI * 16) + mi * 16 + r16;
      af[mi] = *(const bf16x8*)(As + row * BK + q * 8);
    }
#pragma unroll
    for (int ni = 0; ni < NI; ++ni) {
      const int col = wn * (NI * 16) + ni * 16 + r16;
      wf[ni] = *(const bf16x8*)(Ws + col * BK + q * 8);
    }
#pragma unroll
    for (int mi = 0; mi < MI; ++mi)
#pragma unroll
      for (int ni = 0; ni < NI; ++ni)
        acc[mi][ni] = __builtin_amdgcn_mfma_f32_16x16x32_bf16(
            af[mi], wf[ni], acc[mi][ni], 0, 0, 0);
    __syncthreads();
  }

  // Epilogue. C/D layout (m89/m91 verified): col = lane&15, row = (lane>>4)*4+reg.
#pragma unroll
  for (int ni = 0; ni < NI; ++ni) {
    const int col = bn + wn * (NI * 16) + ni * 16 + r16;
    const float bv = bias[col];
#pragma unroll
    for (int mi = 0; mi < MI; ++mi) {
      const int rbase = bm + wm * (MI * 16) + mi * 16 + q * 4;
#pragma unroll
      for (int r = 0; r < 4; ++r) {
        const float v = acc[mi][ni][r] + bv;
        if constexpr (sizeof(TC) == 2)
          Cq[(size_t)(rbase + r) * ldc + col] = f2b(v);
        else
          Cq[(size_t)(rbase + r) * ldc + col] = v;
      }
    }
  }
}

// ---------------------------------------------------------------------------
// Fused: encoder LN (stats over the 2048-wide [mu|lv] row) + KL partials
// (spread atomics) + causal transform. One block (256 thr) per token.
// ---------------------------------------------------------------------------
__global__ __launch_bounds__(256) void kl_causal_kernel(
    const uint16_t* __restrict__ lv, uint16_t* __restrict__ mu,
    const float* __restrict__ g, const float* __restrict__ b,
    const float* __restrict__ dag_w)
{
  __shared__ __align__(16) float zsh[1024];
  __shared__ float dg[256];
  __shared__ float red[8];
  __shared__ float red2[4];
  const int tid = threadIdx.x;
  const int tok = blockIdx.x;
  const int e0  = tid * 4;

  {  // dag matrix: tril(softplus(dag_w), -1)
    const int di = tid >> 4, dj = tid & 15;
    dg[tid] = (dj < di) ? log1pf(expf(dag_w[tid])) : 0.f;
  }

  const uint16_t* lvp = lv + (size_t)tok * 1024;
  uint16_t*       mup = mu + (size_t)tok * 1024;

  const u16x4 m4 = *(const u16x4*)(mup + e0);
  const u16x4 l4 = *(const u16x4*)(lvp + e0);
  float xm[4], xl[4];
  float s1 = 0.f, s2 = 0.f;
#pragma unroll
  for (int k = 0; k < 4; ++k) {
    xm[k] = b2f(m4[k]);
    xl[k] = b2f(l4[k]);
    s1 += xm[k] + xl[k];
    s2 += xm[k] * xm[k] + xl[k] * xl[k];
  }
#pragma unroll
  for (int m = 1; m < 64; m <<= 1) {
    s1 += __shfl_xor(s1, m);
    s2 += __shfl_xor(s2, m);
  }
  const int wave = tid >> 6, lane = tid & 63;
  if (lane == 0) { red[wave] = s1; red[4 + wave] = s2; }
  __syncthreads();
  s1 = red[0] + red[1] + red[2] + red[3];
  s2 = red[4] + red[5] + red[6] + red[7];
  const float mean = s1 * (1.f / 2048.f);
  const float var  = s2 * (1.f / 2048.f) - mean * mean;
  const float rs   = rsqrtf(var + 1e-5f);

  const f32x4 g4m = *(const f32x4*)(g + e0);
  const f32x4 b4m = *(const f32x4*)(b + e0);
  const f32x4 g4l = *(const f32x4*)(g + 1024 + e0);
  const f32x4 b4l = *(const f32x4*)(b + 1024 + e0);
  float kl = 0.f;
  f32x4 z;
#pragma unroll
  for (int k = 0; k < 4; ++k) {
    z[k] = (xm[k] - mean) * rs * g4m[k] + b4m[k];
    const float y = (xl[k] - mean) * rs * g4l[k] + b4l[k];
    kl += 1.f + y - z[k] * z[k] - expf(y);
  }
  *(f32x4*)(zsh + e0) = z;
#pragma unroll
  for (int m = 1; m < 64; m <<= 1) kl += __shfl_xor(kl, m);
  if (lane == 0) red2[wave] = kl;
  __syncthreads();  // covers zsh, dg, red2
  if (tid == 0)
    atomicAdd(&g_part[tok & 255], red2[0] + red2[1] + red2[2] + red2[3]);

  // causal: thread covers elems [e0, e0+4) -> concept i = e0>>6, dims d0..d0+3
  const int i  = e0 >> 6;
  const int d0 = e0 & 63;
  f32x4 s = *(const f32x4*)(zsh + e0);
  for (int j = 0; j < i; ++j) {
    const float w = dg[i * 16 + j];
    const f32x4 zj = *(const f32x4*)(zsh + j * 64 + d0);
    s[0] += w * zj[0]; s[1] += w * zj[1]; s[2] += w * zj[2]; s[3] += w * zj[3];
  }
  u16x4 o;
#pragma unroll
  for (int k = 0; k < 4; ++k) o[k] = f2b(s[k]);
  *(u16x4*)(mup + e0) = o;
}

// ---------------------------------------------------------------------------
// LayerNorm(1024) + ReLU, in-place on bf16 rows, one block (256 thr) per row.
// ---------------------------------------------------------------------------
__global__ __launch_bounds__(256) void ln_relu_kernel(
    uint16_t* __restrict__ data, const float* __restrict__ g,
    const float* __restrict__ b)
{
  const int tid = threadIdx.x;
  const int e0  = tid * 4;
  uint16_t* p = data + (size_t)blockIdx.x * 1024;

  const u16x4 v4 = *(const u16x4*)(p + e0);
  float x[4];
  float s1 = 0.f, s2 = 0.f;
#pragma unroll
  for (int k = 0; k < 4; ++k) {
    x[k] = b2f(v4[k]);
    s1 += x[k];
    s2 += x[k] * x[k];
  }
#pragma unroll
  for (int m = 1; m < 64; m <<= 1) {
    s1 += __shfl_xor(s1, m);
    s2 += __shfl_xor(s2, m);
  }
  __shared__ float red[8];
  const int wave = tid >> 6, lane = tid & 63;
  if (lane == 0) { red[wave] = s1; red[4 + wave] = s2; }
  __syncthreads();
  s1 = red[0] + red[1] + red[2] + red[3];
  s2 = red[4] + red[5] + red[6] + red[7];
  const float mean = s1 * (1.f / 1024.f);
  const float var  = s2 * (1.f / 1024.f) - mean * mean;
  const float rs   = rsqrtf(var + 1e-5f);

  const f32x4 g4 = *(const f32x4*)(g + e0);
  const f32x4 b4 = *(const f32x4*)(b + e0);
  u16x4 o;
#pragma unroll
  for (int k = 0; k < 4; ++k) {
    const float y = (x[k] - mean) * rs * g4[k] + b4[k];
    o[k] = f2b(fmaxf(y, 0.f));
  }
  *(u16x4*)(p + e0) = o;
}

// ---------------------------------------------------------------------------
// LN(64) + ReLU per (token, concept) group. 16 groups per block; each group
// handled by a 16-lane chunk (4 elems/lane, ushort4). In-place bf16.
// ---------------------------------------------------------------------------
__global__ __launch_bounds__(256) void ln_cd_kernel(
    uint16_t* __restrict__ t, const float* __restrict__ cg,
    const float* __restrict__ cbt)
{
  const int tid = threadIdx.x;
  const int sub = tid >> 4;    // group within block (0..15)
  const int le  = tid & 15;    // 16-lane chunk position
  const int gidx = blockIdx.x * 16 + sub;
  const int c = gidx & 15;
  const size_t off = (size_t)gidx * 64 + le * 4;

  const u16x4 v4 = *(const u16x4*)(t + off);
  float x[4];
  float s1 = 0.f, s2 = 0.f;
#pragma unroll
  for (int k = 0; k < 4; ++k) {
    x[k] = b2f(v4[k]);
    s1 += x[k];
    s2 += x[k] * x[k];
  }
#pragma unroll
  for (int m = 1; m < 16; m <<= 1) {  // reduce within the 16-lane chunk
    s1 += __shfl_xor(s1, m);
    s2 += __shfl_xor(s2, m);
  }
  const float mean = s1 * (1.f / 64.f);
  const float var  = s2 * (1.f / 64.f) - mean * mean;
  const float rs   = rsqrtf(var + 1e-5f);

  const f32x4 cg4  = *(const f32x4*)(cg + c * 64 + le * 4);
  const f32x4 cbt4 = *(const f32x4*)(cbt + c * 64 + le * 4);
  u16x4 o;
#pragma unroll
  for (int k = 0; k < 4; ++k) {
    const float y = (x[k] - mean) * rs * cg4[k] + cbt4[k];
    o[k] = f2b(fmaxf(y, 0.f));
  }
  *(u16x4*)(t + off) = o;
}

// ---------------------------------------------------------------------------
// recon partials: sum (x_recon - x)^2, float4, spread atomics over 256 slots.
// ---------------------------------------------------------------------------
__global__ __launch_bounds__(256) void recon_kernel(
    const float* __restrict__ xr, const float* __restrict__ x, int n4)
{
  const f32x4* xr4 = (const f32x4*)xr;
  const f32x4* x4  = (const f32x4*)x;
  float s = 0.f;
  for (int i = blockIdx.x * 256 + threadIdx.x; i < n4; i += gridDim.x * 256) {
    const f32x4 d = xr4[i] - x4[i];
    s += d[0] * d[0] + d[1] * d[1] + d[2] * d[2] + d[3] * d[3];
  }
#pragma unroll
  for (int m = 1; m < 64; m <<= 1) s += __shfl_xor(s, m);
  __shared__ float red[4];
  const int wave = threadIdx.x >> 6, lane = threadIdx.x & 63;
  if (lane == 0) red[wave] = s;
  __syncthreads();
  if (threadIdx.x == 0)
    atomicAdd(&g_part[256 + (blockIdx.x & 255)], red[0] + red[1] + red[2] + red[3]);
}

// ---------------------------------------------------------------------------
// init: zero 512 partial slots; dag_loss = sum(tril softplus) + 16.
// ---------------------------------------------------------------------------
__global__ __launch_bounds__(256) void dag_init_kernel(
    const float* __restrict__ dag_w)
{
  const int t = threadIdx.x;
  g_part[t] = 0.f;
  g_part[256 + t] = 0.f;
  const int i = t >> 4, j = t & 15;
  const float v = (j < i) ? log1pf(expf(dag_w[t])) : 0.f;
  float s = v;
#pragma unroll
  for (int m = 1; m < 64; m <<= 1) s += __shfl_xor(s, m);
  __shared__ float red[4];
  const int wave = t >> 6, lane = t & 63;
  if (lane == 0) red[wave] = s;
  __syncthreads();
  if (t == 0)
    g_scal[2] = red[0] + red[1] + red[2] + red[3] + 16.f;  // trace(expm)=C exactly
}

// ---------------------------------------------------------------------------
// finalize: sum the 256+256 partial slots, emit the 4 loss scalars.
// ---------------------------------------------------------------------------
__global__ __launch_bounds__(256) void finalize_kernel(float* __restrict__ out_tail)
{
  const int tid = threadIdx.x;
  float kl = g_part[tid];
  float rc = g_part[256 + tid];
#pragma unroll
  for (int m = 1; m < 64; m <<= 1) {
    kl += __shfl_xor(kl, m);
    rc += __shfl_xor(rc, m);
  }
  __shared__ float red[8];
  const int wave = tid >> 6, lane = tid & 63;
  if (lane == 0) { red[wave] = kl; red[4 + wave] = rc; }
  __syncthreads();
  if (tid == 0) {
    const float kls = red[0] + red[1] + red[2] + red[3];
    const float rcs = red[4] + red[5] + red[6] + red[7];
    const float kl_l   = -0.5f * kls * (1.f / (16384.f * 1024.f));
    const float recon  = rcs * (1.f / 16777216.f);
    const float dagl   = g_scal[2];
    out_tail[0] = recon + 0.3f * kl_l + 1.0f * dagl;
    out_tail[1] = kl_l;
    out_tail[2] = recon;
    out_tail[3] = dagl;
  }
}

// ---------------------------------------------------------------------------
extern "C" void kernel_launch(void* const* d_in, const int* in_sizes, int n_in,
                              void* d_out, int out_size, void* d_ws, size_t ws_size,
                              hipStream_t stream) {
  const float* x      = (const float*)d_in[0];
  const float* enc_w  = (const float*)d_in[1];
  const float* enc_b  = (const float*)d_in[2];
  const float* enc_g  = (const float*)d_in[3];
  const float* enc_bt = (const float*)d_in[4];
  const float* dag_w  = (const float*)d_in[5];
  const float* cw1    = (const float*)d_in[6];
  const float* cb1    = (const float*)d_in[7];
  const float* cg     = (const float*)d_in[8];
  const float* cbt    = (const float*)d_in[9];
  const float* cw1f   = cw1;
  const float* cw2    = (const float*)d_in[10];
  const float* cb2    = (const float*)d_in[11];
  const float* dec_w1 = (const float*)d_in[12];
  const float* dec_b1 = (const float*)d_in[13];
  const float* dec_g  = (const float*)d_in[14];
  const float* dec_bt = (const float*)d_in[15];
  const float* dec_w2 = (const float*)d_in[16];
  const float* dec_b2 = (const float*)d_in[17];
  (void)cw1f;

  uint16_t* S    = (uint16_t*)d_ws;                       // [16384x1024] bf16, 32 MiB
  uint16_t* Wbf  = (uint16_t*)((char*)d_ws + (size_t)NTOK * DIM * 2);
  uint16_t* ewb  = Wbf;                                   // enc_w   2,097,152
  uint16_t* d1b  = Wbf + 2097152;                         // dec_w1  1,048,576
  uint16_t* d2b  = Wbf + 3145728;                         // dec_w2  1,048,576
  uint16_t* c1b  = Wbf + 4194304;                         // cw1       65,536
  uint16_t* c2b  = Wbf + 4259840;                         // cw2       65,536

  uint16_t* Obf  = (uint16_t*)d_out;                      // bf16 scratch (lower half)
  uint16_t* xbf  = Obf + (size_t)NOUT_ELEMS;              // x_bf16 (upper half)
  float*    O    = (float*)d_out;                         // final fp32 x_recon + losses

  // 1. zero partials + dag_loss
  dag_init_kernel<<<1, 256, 0, stream>>>(dag_w);

  // 1b. convert x and all weights to bf16
  cvt_x_kernel<<<NOUT_ELEMS / 8 / 256, 256, 0, stream>>>(x, xbf);
  cvt_weights_kernel<<<2112, 256, 0, stream>>>(enc_w, dec_w1, dec_w2, cw1, cw2, Wbf);

  // 2a. mu_pre = x @ enc_w[0:1024]^T + enc_b[0:1024] -> Obf
  gemm_bt_kernel<128, 128, 32, 2, 2, uint16_t>
      <<<dim3(128, 8, 1), 256, 0, stream>>>(
      xbf, ewb, enc_b, Obf, DIM, DIM, DIM, DIM, 0, 0, 0, 0);

  // 2b. lv_pre = x @ enc_w[1024:2048]^T + enc_b[1024:2048] -> S
  gemm_bt_kernel<128, 128, 32, 2, 2, uint16_t>
      <<<dim3(128, 8, 1), 256, 0, stream>>>(
      xbf, ewb + (size_t)DIM * DIM, enc_b + DIM, S, DIM, DIM, DIM, DIM,
      0, 0, 0, 0);

  // 3. fused LN + KL + causal: z_causal overwrites mu in Obf (xbf now dead)
  kl_causal_kernel<<<NTOK, 256, 0, stream>>>(S, Obf, enc_g, enc_bt, dag_w);

  // 4. concept linear 1 (block-diag): t = z_causal @ cw1^T + cb1 -> S
  gemm_bt_kernel<128, 64, 32, 4, 1, uint16_t>
      <<<dim3(128, 1, 16), 256, 0, stream>>>(
      Obf, c1b, cb1, S, CD, DIM, CD, DIM, 64, 4096, 64, 64);

  // 5. per-concept LN(64) + ReLU (in-place on S)
  ln_cd_kernel<<<NTOK * NC / 16, 256, 0, stream>>>(S, cg, cbt);

  // 6. concept linear 2: z_t = t @ cw2^T + cb2 -> Obf
  gemm_bt_kernel<128, 64, 32, 4, 1, uint16_t>
      <<<dim3(128, 1, 16), 256, 0, stream>>>(
      S, c2b, cb2, Obf, CD, DIM, CD, DIM, 64, 4096, 64, 64);

  // 7. decoder GEMM1: d_pre = z_t @ dec_w1^T + dec_b1 -> S
  gemm_bt_kernel<128, 128, 32, 2, 2, uint16_t>
      <<<dim3(128, 8, 1), 256, 0, stream>>>(
      Obf, d1b, dec_b1, S, DIM, DIM, DIM, DIM, 0, 0, 0, 0);

  // 8. decoder LN + ReLU (in-place on S)
  ln_relu_kernel<<<NTOK, 256, 0, stream>>>(S, dec_g, dec_bt);

  // 9. decoder GEMM2: x_recon = d @ dec_w2^T + dec_b2 -> O (fp32, overwrites Obf)
  gemm_bt_kernel<128, 128, 32, 2, 2, float>
      <<<dim3(128, 8, 1), 256, 0, stream>>>(
      S, d2b, dec_b2, O, DIM, DIM, DIM, DIM, 0, 0, 0, 0);

  // 10. recon loss partials (fp32 vs fp32, float4)
  recon_kernel<<<1024, 256, 0, stream>>>(O, x, NOUT_ELEMS / 4);

  // 11. final scalars
  finalize_kernel<<<1, 256, 0, stream>>>(O + (size_t)NOUT_ELEMS);
}

// Round 8
// 459.456 us; speedup vs baseline: 1.8149x; 1.0980x over previous
//
#include <hip/hip_runtime.h>
#include <stdint.h>

// ---------------------------------------------------------------------------
// CausalVAELayer forward, MI355X (gfx950). FP32 in / FP32 out.
// Internally: bf16 MFMA GEMMs, fp32 acc, bf16 intermediates.
// B=8,S=2048,D=1024,C=16,CD=64,L=1024. Tokens N=16384.
// dag strictly-lower-triangular => nilpotent => trace(expm(dag)) == 16 exactly.
//
// ROUND 8: GEMM K-loop rework. BK=64 (half the barrier drains vs BK=32),
// XOR chunk swizzle (chunk ^= row&7) applied in both the global_load_lds
// SOURCE address and the ds_read fragment address -> 8/16-way LDS bank
// conflicts become perfect 2-way (free). Encoder GEMMs merged into one
// N=2048 dispatch with split epilogue (mu->Obf, lv->S).
// Workspace: S (32 MiB) + Wbf (8.25 MiB) = 40.3 MiB.
// ---------------------------------------------------------------------------

#define NTOK   16384
#define DIM    1024
#define NC     16
#define CD     64
#define NOUT_ELEMS 16777216  // NTOK*DIM

typedef float f32x4 __attribute__((ext_vector_type(4)));
typedef __bf16 bf16x8 __attribute__((ext_vector_type(8)));
typedef unsigned short u16x4 __attribute__((ext_vector_type(4)));
typedef unsigned short u16x8 __attribute__((ext_vector_type(8)));

__device__ float g_scal[3];    // [2]=dag_loss
__device__ float g_part[512];  // [0..256)=kl partials, [256..512)=recon partials

__device__ __forceinline__ float b2f(uint16_t u) {
  union { uint32_t i; float f; } v; v.i = ((uint32_t)u) << 16; return v.f;
}
__device__ __forceinline__ uint16_t f2b(float f) {
  union { float f; uint32_t i; } v; v.f = f;
  uint32_t x = v.i;
  return (uint16_t)((x + 0x7fffu + ((x >> 16) & 1u)) >> 16);  // RNE
}

__device__ __forceinline__ void gload_lds16(const uint16_t* g, uint16_t* l) {
  __builtin_amdgcn_global_load_lds(
      (const __attribute__((address_space(1))) void*)g,
      (__attribute__((address_space(3))) void*)l, 16, 0, 0);
}

// convert 8 fp32 -> 8 bf16 (RNE), 16B store
__device__ __forceinline__ void cvt8(const float* s, uint16_t* d) {
  const f32x4 a = *(const f32x4*)s;
  const f32x4 b = *(const f32x4*)(s + 4);
  u16x8 o;
  o[0]=f2b(a[0]); o[1]=f2b(a[1]); o[2]=f2b(a[2]); o[3]=f2b(a[3]);
  o[4]=f2b(b[0]); o[5]=f2b(b[1]); o[6]=f2b(b[2]); o[7]=f2b(b[3]);
  *(u16x8*)d = o;
}

__global__ __launch_bounds__(256) void cvt_x_kernel(
    const float* __restrict__ src, uint16_t* __restrict__ dst)
{
  const int i = blockIdx.x * 256 + threadIdx.x;
  cvt8(src + (size_t)i * 8, dst + (size_t)i * 8);
}

// weights, concatenated into Wbf: [enc_w 2M | dec_w1 1M | dec_w2 1M | cw1 64K | cw2 64K]
__global__ __launch_bounds__(256) void cvt_weights_kernel(
    const float* __restrict__ ew, const float* __restrict__ d1,
    const float* __restrict__ d2, const float* __restrict__ c1,
    const float* __restrict__ c2, uint16_t* __restrict__ out)
{
  const int i = blockIdx.x * 256 + threadIdx.x;  // elem8 idx, total 540672
  const float* src; uint16_t* dst; int off;
  if (i < 262144)      { src = ew; dst = out;           off = i; }
  else if (i < 393216) { src = d1; dst = out + 2097152; off = i - 262144; }
  else if (i < 524288) { src = d2; dst = out + 3145728; off = i - 393216; }
  else if (i < 532480) { src = c1; dst = out + 4194304; off = i - 524288; }
  else                 { src = c2; dst = out + 4259840; off = i - 532480; }
  cvt8(src + (size_t)off * 8, dst + (size_t)off * 8);
}

// ---------------------------------------------------------------------------
// GEMM: C[m,n] = sum_k A[m,k]*W[n,k] + bias[n]. A,W bf16; bias fp32; C bf16/f32.
// BK=64, global_load_lds width-16 staging with XOR chunk swizzle:
//   LDS slot (row, p) holds global chunk p ^ (row&7)  (chunk = 8 elems = 16B).
//   Staging: lane (tid) -> slot (i*32 + tid>>3, tid&7), fetches global chunk
//   (tid&7) ^ (row&7). Fragment read: chunk c -> physical c ^ (row&7).
//   16 fragment rows x xor-permuted chunks => perfect 2-way bank aliasing.
// SPLIT: epilogue routes cols [0,1024) -> C0, [1024,2048) -> C1 (encoder).
// blockIdx.z (cz) shifts by cs* for the per-concept block-diagonal GEMMs.
// ---------------------------------------------------------------------------
template<int BM, int BN, int WM, int WN, typename TC, bool SPLIT>
__global__ __launch_bounds__(256) void gemm_bt_kernel(
    const uint16_t* __restrict__ A, const uint16_t* __restrict__ Wm,
    const float* __restrict__ bias, TC* __restrict__ C0, TC* __restrict__ C1,
    int K, int lda, int ldw, int ldc,
    int csA, int csW, int csB, int csC)
{
  constexpr int BK = 64;
  static_assert(WM * WN == 4, "4 waves");
  constexpr int MI = BM / (WM * 16);
  constexpr int NI = BN / (WN * 16);
  constexpr int AI = (BM * BK * 2) / 4096;   // 4096B (256 lanes x 16B) per issue
  constexpr int WI = (BN * BK * 2) / 4096;
  static_assert((BM * BK * 2) % 4096 == 0 && (BN * BK * 2) % 4096 == 0, "");

  __shared__ __align__(16) uint16_t lds[BM * BK + BN * BK];
  uint16_t* As = lds;
  uint16_t* Ws = lds + BM * BK;

  const int cz = blockIdx.z;
  A    += (size_t)cz * csA;
  Wm   += (size_t)cz * csW;
  bias += cz * csB;

  const int tid  = threadIdx.x;
  const int wave = tid >> 6;
  const int lane = tid & 63;
  const int q    = lane >> 4;
  const int r16  = lane & 15;
  const int wm   = wave / WN;
  const int wn   = wave % WN;

  const int bm = blockIdx.x * BM;
  const int bn = blockIdx.y * BN;

  const int sr = tid >> 3;               // row within a 32-row issue
  const int pc = tid & 7;                // physical chunk slot (16B units)

  f32x4 acc[MI][NI] = {};

  for (int k0 = 0; k0 < K; k0 += BK) {
#pragma unroll
    for (int i = 0; i < AI; ++i) {
      const int r = i * 32 + sr;
      const int c = pc ^ (r & 7);        // global chunk to land in slot pc
      const uint16_t* g = A + (size_t)(bm + r) * lda + k0 + c * 8;
      gload_lds16(g, (uint16_t*)((char*)As + i * 4096 + wave * 1024));
    }
#pragma unroll
    for (int i = 0; i < WI; ++i) {
      const int r = i * 32 + sr;
      const int c = pc ^ (r & 7);
      const uint16_t* g = Wm + (size_t)(bn + r) * ldw + k0 + c * 8;
      gload_lds16(g, (uint16_t*)((char*)Ws + i * 4096 + wave * 1024));
    }
    __syncthreads();

#pragma unroll
    for (int ks = 0; ks < 2; ++ks) {     // two K=32 MFMA steps per BK=64 tile
      bf16x8 af[MI], wf[NI];
#pragma unroll
      for (int mi = 0; mi < MI; ++mi) {
        const int row = wm * (MI * 16) + mi * 16 + r16;
        const int c   = (ks * 4 + q) ^ (row & 7);
        af[mi] = *(const bf16x8*)(As + row * BK + c * 8);
      }
#pragma unroll
      for (int ni = 0; ni < NI; ++ni) {
        const int col = wn * (NI * 16) + ni * 16 + r16;
        const int c   = (ks * 4 + q) ^ (col & 7);
        wf[ni] = *(const bf16x8*)(Ws + col * BK + c * 8);
      }
#pragma unroll
      for (int mi = 0; mi < MI; ++mi)
#pragma unroll
        for (int ni = 0; ni < NI; ++ni)
          acc[mi][ni] = __builtin_amdgcn_mfma_f32_16x16x32_bf16(
              af[mi], wf[ni], acc[mi][ni], 0, 0, 0);
    }
    __syncthreads();
  }

  // Epilogue. C/D layout (m89/m91 verified): col = lane&15, row = (lane>>4)*4+reg.
  TC* Cq = C0;
  int cb = bn;                            // store-column base
  if constexpr (SPLIT) {
    if (bn >= 1024) { Cq = C1; cb = bn - 1024; }
  }
  Cq += (size_t)cz * csC;
#pragma unroll
  for (int ni = 0; ni < NI; ++ni) {
    const int loc = wn * (NI * 16) + ni * 16 + r16;
    const float bv = bias[bn + loc];
#pragma unroll
    for (int mi = 0; mi < MI; ++mi) {
      const int rbase = bm + wm * (MI * 16) + mi * 16 + q * 4;
#pragma unroll
      for (int r = 0; r < 4; ++r) {
        const float v = acc[mi][ni][r] + bv;
        if constexpr (sizeof(TC) == 2)
          Cq[(size_t)(rbase + r) * ldc + cb + loc] = f2b(v);
        else
          Cq[(size_t)(rbase + r) * ldc + cb + loc] = v;
      }
    }
  }
}

// ---------------------------------------------------------------------------
// Fused: encoder LN (stats over the 2048-wide [mu|lv] row) + KL partials
// (spread atomics) + causal transform. One block (256 thr) per token.
// ---------------------------------------------------------------------------
__global__ __launch_bounds__(256) void kl_causal_kernel(
    const uint16_t* __restrict__ lv, uint16_t* __restrict__ mu,
    const float* __restrict__ g, const float* __restrict__ b,
    const float* __restrict__ dag_w)
{
  __shared__ __align__(16) float zsh[1024];
  __shared__ float dg[256];
  __shared__ float red[8];
  __shared__ float red2[4];
  const int tid = threadIdx.x;
  const int tok = blockIdx.x;
  const int e0  = tid * 4;

  {  // dag matrix: tril(softplus(dag_w), -1)
    const int di = tid >> 4, dj = tid & 15;
    dg[tid] = (dj < di) ? log1pf(expf(dag_w[tid])) : 0.f;
  }

  const uint16_t* lvp = lv + (size_t)tok * 1024;
  uint16_t*       mup = mu + (size_t)tok * 1024;

  const u16x4 m4 = *(const u16x4*)(mup + e0);
  const u16x4 l4 = *(const u16x4*)(lvp + e0);
  float xm[4], xl[4];
  float s1 = 0.f, s2 = 0.f;
#pragma unroll
  for (int k = 0; k < 4; ++k) {
    xm[k] = b2f(m4[k]);
    xl[k] = b2f(l4[k]);
    s1 += xm[k] + xl[k];
    s2 += xm[k] * xm[k] + xl[k] * xl[k];
  }
#pragma unroll
  for (int m = 1; m < 64; m <<= 1) {
    s1 += __shfl_xor(s1, m);
    s2 += __shfl_xor(s2, m);
  }
  const int wave = tid >> 6, lane = tid & 63;
  if (lane == 0) { red[wave] = s1; red[4 + wave] = s2; }
  __syncthreads();
  s1 = red[0] + red[1] + red[2] + red[3];
  s2 = red[4] + red[5] + red[6] + red[7];
  const float mean = s1 * (1.f / 2048.f);
  const float var  = s2 * (1.f / 2048.f) - mean * mean;
  const float rs   = rsqrtf(var + 1e-5f);

  const f32x4 g4m = *(const f32x4*)(g + e0);
  const f32x4 b4m = *(const f32x4*)(b + e0);
  const f32x4 g4l = *(const f32x4*)(g + 1024 + e0);
  const f32x4 b4l = *(const f32x4*)(b + 1024 + e0);
  float kl = 0.f;
  f32x4 z;
#pragma unroll
  for (int k = 0; k < 4; ++k) {
    z[k] = (xm[k] - mean) * rs * g4m[k] + b4m[k];
    const float y = (xl[k] - mean) * rs * g4l[k] + b4l[k];
    kl += 1.f + y - z[k] * z[k] - expf(y);
  }
  *(f32x4*)(zsh + e0) = z;
#pragma unroll
  for (int m = 1; m < 64; m <<= 1) kl += __shfl_xor(kl, m);
  if (lane == 0) red2[wave] = kl;
  __syncthreads();  // covers zsh, dg, red2
  if (tid == 0)
    atomicAdd(&g_part[tok & 255], red2[0] + red2[1] + red2[2] + red2[3]);

  // causal: thread covers elems [e0, e0+4) -> concept i = e0>>6, dims d0..d0+3
  const int i  = e0 >> 6;
  const int d0 = e0 & 63;
  f32x4 s = *(const f32x4*)(zsh + e0);
  for (int j = 0; j < i; ++j) {
    const float w = dg[i * 16 + j];
    const f32x4 zj = *(const f32x4*)(zsh + j * 64 + d0);
    s[0] += w * zj[0]; s[1] += w * zj[1]; s[2] += w * zj[2]; s[3] += w * zj[3];
  }
  u16x4 o;
#pragma unroll
  for (int k = 0; k < 4; ++k) o[k] = f2b(s[k]);
  *(u16x4*)(mup + e0) = o;
}

// ---------------------------------------------------------------------------
// LayerNorm(1024) + ReLU, in-place on bf16 rows, one block (256 thr) per row.
// ---------------------------------------------------------------------------
__global__ __launch_bounds__(256) void ln_relu_kernel(
    uint16_t* __restrict__ data, const float* __restrict__ g,
    const float* __restrict__ b)
{
  const int tid = threadIdx.x;
  const int e0  = tid * 4;
  uint16_t* p = data + (size_t)blockIdx.x * 1024;

  const u16x4 v4 = *(const u16x4*)(p + e0);
  float x[4];
  float s1 = 0.f, s2 = 0.f;
#pragma unroll
  for (int k = 0; k < 4; ++k) {
    x[k] = b2f(v4[k]);
    s1 += x[k];
    s2 += x[k] * x[k];
  }
#pragma unroll
  for (int m = 1; m < 64; m <<= 1) {
    s1 += __shfl_xor(s1, m);
    s2 += __shfl_xor(s2, m);
  }
  __shared__ float red[8];
  const int wave = tid >> 6, lane = tid & 63;
  if (lane == 0) { red[wave] = s1; red[4 + wave] = s2; }
  __syncthreads();
  s1 = red[0] + red[1] + red[2] + red[3];
  s2 = red[4] + red[5] + red[6] + red[7];
  const float mean = s1 * (1.f / 1024.f);
  const float var  = s2 * (1.f / 1024.f) - mean * mean;
  const float rs   = rsqrtf(var + 1e-5f);

  const f32x4 g4 = *(const f32x4*)(g + e0);
  const f32x4 b4 = *(const f32x4*)(b + e0);
  u16x4 o;
#pragma unroll
  for (int k = 0; k < 4; ++k) {
    const float y = (x[k] - mean) * rs * g4[k] + b4[k];
    o[k] = f2b(fmaxf(y, 0.f));
  }
  *(u16x4*)(p + e0) = o;
}

// ---------------------------------------------------------------------------
// LN(64) + ReLU per (token, concept) group. 16 groups per block; each group
// handled by a 16-lane chunk (4 elems/lane, ushort4). In-place bf16.
// ---------------------------------------------------------------------------
__global__ __launch_bounds__(256) void ln_cd_kernel(
    uint16_t* __restrict__ t, const float* __restrict__ cg,
    const float* __restrict__ cbt)
{
  const int tid = threadIdx.x;
  const int sub = tid >> 4;
  const int le  = tid & 15;
  const int gidx = blockIdx.x * 16 + sub;
  const int c = gidx & 15;
  const size_t off = (size_t)gidx * 64 + le * 4;

  const u16x4 v4 = *(const u16x4*)(t + off);
  float x[4];
  float s1 = 0.f, s2 = 0.f;
#pragma unroll
  for (int k = 0; k < 4; ++k) {
    x[k] = b2f(v4[k]);
    s1 += x[k];
    s2 += x[k] * x[k];
  }
#pragma unroll
  for (int m = 1; m < 16; m <<= 1) {
    s1 += __shfl_xor(s1, m);
    s2 += __shfl_xor(s2, m);
  }
  const float mean = s1 * (1.f / 64.f);
  const float var  = s2 * (1.f / 64.f) - mean * mean;
  const float rs   = rsqrtf(var + 1e-5f);

  const f32x4 cg4  = *(const f32x4*)(cg + c * 64 + le * 4);
  const f32x4 cbt4 = *(const f32x4*)(cbt + c * 64 + le * 4);
  u16x4 o;
#pragma unroll
  for (int k = 0; k < 4; ++k) {
    const float y = (x[k] - mean) * rs * cg4[k] + cbt4[k];
    o[k] = f2b(fmaxf(y, 0.f));
  }
  *(u16x4*)(t + off) = o;
}

// ---------------------------------------------------------------------------
// recon partials: sum (x_recon - x)^2, float4, spread atomics over 256 slots.
// ---------------------------------------------------------------------------
__global__ __launch_bounds__(256) void recon_kernel(
    const float* __restrict__ xr, const float* __restrict__ x, int n4)
{
  const f32x4* xr4 = (const f32x4*)xr;
  const f32x4* x4  = (const f32x4*)x;
  float s = 0.f;
  for (int i = blockIdx.x * 256 + threadIdx.x; i < n4; i += gridDim.x * 256) {
    const f32x4 d = xr4[i] - x4[i];
    s += d[0] * d[0] + d[1] * d[1] + d[2] * d[2] + d[3] * d[3];
  }
#pragma unroll
  for (int m = 1; m < 64; m <<= 1) s += __shfl_xor(s, m);
  __shared__ float red[4];
  const int wave = threadIdx.x >> 6, lane = threadIdx.x & 63;
  if (lane == 0) red[wave] = s;
  __syncthreads();
  if (threadIdx.x == 0)
    atomicAdd(&g_part[256 + (blockIdx.x & 255)], red[0] + red[1] + red[2] + red[3]);
}

// ---------------------------------------------------------------------------
// init: zero 512 partial slots; dag_loss = sum(tril softplus) + 16.
// ---------------------------------------------------------------------------
__global__ __launch_bounds__(256) void dag_init_kernel(
    const float* __restrict__ dag_w)
{
  const int t = threadIdx.x;
  g_part[t] = 0.f;
  g_part[256 + t] = 0.f;
  const int i = t >> 4, j = t & 15;
  const float v = (j < i) ? log1pf(expf(dag_w[t])) : 0.f;
  float s = v;
#pragma unroll
  for (int m = 1; m < 64; m <<= 1) s += __shfl_xor(s, m);
  __shared__ float red[4];
  const int wave = t >> 6, lane = t & 63;
  if (lane == 0) red[wave] = s;
  __syncthreads();
  if (t == 0)
    g_scal[2] = red[0] + red[1] + red[2] + red[3] + 16.f;  // trace(expm)=C exactly
}

// ---------------------------------------------------------------------------
// finalize: sum the 256+256 partial slots, emit the 4 loss scalars.
// ---------------------------------------------------------------------------
__global__ __launch_bounds__(256) void finalize_kernel(float* __restrict__ out_tail)
{
  const int tid = threadIdx.x;
  float kl = g_part[tid];
  float rc = g_part[256 + tid];
#pragma unroll
  for (int m = 1; m < 64; m <<= 1) {
    kl += __shfl_xor(kl, m);
    rc += __shfl_xor(rc, m);
  }
  __shared__ float red[8];
  const int wave = tid >> 6, lane = tid & 63;
  if (lane == 0) { red[wave] = kl; red[4 + wave] = rc; }
  __syncthreads();
  if (tid == 0) {
    const float kls = red[0] + red[1] + red[2] + red[3];
    const float rcs = red[4] + red[5] + red[6] + red[7];
    const float kl_l   = -0.5f * kls * (1.f / (16384.f * 1024.f));
    const float recon  = rcs * (1.f / 16777216.f);
    const float dagl   = g_scal[2];
    out_tail[0] = recon + 0.3f * kl_l + 1.0f * dagl;
    out_tail[1] = kl_l;
    out_tail[2] = recon;
    out_tail[3] = dagl;
  }
}

// ---------------------------------------------------------------------------
extern "C" void kernel_launch(void* const* d_in, const int* in_sizes, int n_in,
                              void* d_out, int out_size, void* d_ws, size_t ws_size,
                              hipStream_t stream) {
  const float* x      = (const float*)d_in[0];
  const float* enc_w  = (const float*)d_in[1];
  const float* enc_b  = (const float*)d_in[2];
  const float* enc_g  = (const float*)d_in[3];
  const float* enc_bt = (const float*)d_in[4];
  const float* dag_w  = (const float*)d_in[5];
  const float* cw1    = (const float*)d_in[6];
  const float* cb1    = (const float*)d_in[7];
  const float* cg     = (const float*)d_in[8];
  const float* cbt    = (const float*)d_in[9];
  const float* cw2    = (const float*)d_in[10];
  const float* cb2    = (const float*)d_in[11];
  const float* dec_w1 = (const float*)d_in[12];
  const float* dec_b1 = (const float*)d_in[13];
  const float* dec_g  = (const float*)d_in[14];
  const float* dec_bt = (const float*)d_in[15];
  const float* dec_w2 = (const float*)d_in[16];
  const float* dec_b2 = (const float*)d_in[17];

  uint16_t* S    = (uint16_t*)d_ws;                       // [16384x1024] bf16, 32 MiB
  uint16_t* Wbf  = (uint16_t*)((char*)d_ws + (size_t)NTOK * DIM * 2);
  uint16_t* ewb  = Wbf;                                   // enc_w   2,097,152
  uint16_t* d1b  = Wbf + 2097152;                         // dec_w1  1,048,576
  uint16_t* d2b  = Wbf + 3145728;                         // dec_w2  1,048,576
  uint16_t* c1b  = Wbf + 4194304;                         // cw1       65,536
  uint16_t* c2b  = Wbf + 4259840;                         // cw2       65,536

  uint16_t* Obf  = (uint16_t*)d_out;                      // bf16 scratch (lower half)
  uint16_t* xbf  = Obf + (size_t)NOUT_ELEMS;              // x_bf16 (upper half)
  float*    O    = (float*)d_out;                         // final fp32 x_recon + losses

  // 1. zero partials + dag_loss
  dag_init_kernel<<<1, 256, 0, stream>>>(dag_w);

  // 1b. convert x and all weights to bf16
  cvt_x_kernel<<<NOUT_ELEMS / 8 / 256, 256, 0, stream>>>(x, xbf);
  cvt_weights_kernel<<<2112, 256, 0, stream>>>(enc_w, dec_w1, dec_w2, cw1, cw2, Wbf);

  // 2. encoder GEMM (merged, N=2048, split epilogue): mu -> Obf, lv -> S
  gemm_bt_kernel<128, 128, 2, 2, uint16_t, true>
      <<<dim3(128, 16, 1), 256, 0, stream>>>(
      xbf, ewb, enc_b, Obf, S, DIM, DIM, DIM, DIM, 0, 0, 0, 0);

  // 3. fused LN + KL + causal: z_causal overwrites mu in Obf (xbf now dead)
  kl_causal_kernel<<<NTOK, 256, 0, stream>>>(S, Obf, enc_g, enc_bt, dag_w);

  // 4. concept linear 1 (block-diag): t = z_causal @ cw1^T + cb1 -> S
  gemm_bt_kernel<128, 64, 4, 1, uint16_t, false>
      <<<dim3(128, 1, 16), 256, 0, stream>>>(
      Obf, c1b, cb1, S, S, CD, DIM, CD, DIM, 64, 4096, 64, 64);

  // 5. per-concept LN(64) + ReLU (in-place on S)
  ln_cd_kernel<<<NTOK * NC / 16, 256, 0, stream>>>(S, cg, cbt);

  // 6. concept linear 2: z_t = t @ cw2^T + cb2 -> Obf
  gemm_bt_kernel<128, 64, 4, 1, uint16_t, false>
      <<<dim3(128, 1, 16), 256, 0, stream>>>(
      S, c2b, cb2, Obf, Obf, CD, DIM, CD, DIM, 64, 4096, 64, 64);

  // 7. decoder GEMM1: d_pre = z_t @ dec_w1^T + dec_b1 -> S
  gemm_bt_kernel<128, 128, 2, 2, uint16_t, false>
      <<<dim3(128, 8, 1), 256, 0, stream>>>(
      Obf, d1b, dec_b1, S, S, DIM, DIM, DIM, DIM, 0, 0, 0, 0);

  // 8. decoder LN + ReLU (in-place on S)
  ln_relu_kernel<<<NTOK, 256, 0, stream>>>(S, dec_g, dec_bt);

  // 9. decoder GEMM2: x_recon = d @ dec_w2^T + dec_b2 -> O (fp32, overwrites Obf)
  gemm_bt_kernel<128, 128, 2, 2, float, false>
      <<<dim3(128, 8, 1), 256, 0, stream>>>(
      S, d2b, dec_b2, O, O, DIM, DIM, DIM, DIM, 0, 0, 0, 0);

  // 10. recon loss partials (fp32 vs fp32, float4)
  recon_kernel<<<1024, 256, 0, stream>>>(O, x, NOUT_ELEMS / 4);

  // 11. final scalars
  finalize_kernel<<<1, 256, 0, stream>>>(O + (size_t)NOUT_ELEMS);
}

// Round 9
// 424.173 us; speedup vs baseline: 1.9659x; 1.0832x over previous
//
#include <hip/hip_runtime.h>
#include <stdint.h>

// ---------------------------------------------------------------------------
// CausalVAELayer forward, MI355X (gfx950). FP32 in / FP32 out.
// Internally: bf16 MFMA GEMMs, fp32 acc, bf16 intermediates.
// B=8,S=2048,D=1024,C=16,CD=64,L=1024. Tokens N=16384.
// dag strictly-lower-triangular => nilpotent => trace(expm(dag)) == 16 exactly.
//
// ROUND 9: (a) concept1 -> LN(64)+ReLU -> concept2 fused into ONE kernel
// (per-block: one concept x 128 tokens; LN in registers via 16-lane shuffle;
// LDS round-trip for the MFMA C->A layout transform, XOR-swizzled, 0-conflict).
// (b) recon loss fused into decoder GEMM2's epilogue (spread atomics).
// Big-GEMM K-loop unchanged from round 8 (BK=64, swizzled global_load_lds).
// Workspace: S (32 MiB) + Wbf (8.25 MiB) = 40.3 MiB.
// ---------------------------------------------------------------------------

#define NTOK   16384
#define DIM    1024
#define NC     16
#define CD     64
#define NOUT_ELEMS 16777216  // NTOK*DIM

typedef float f32x4 __attribute__((ext_vector_type(4)));
typedef __bf16 bf16x8 __attribute__((ext_vector_type(8)));
typedef unsigned short u16x4 __attribute__((ext_vector_type(4)));
typedef unsigned short u16x8 __attribute__((ext_vector_type(8)));

__device__ float g_scal[3];    // [2]=dag_loss
__device__ float g_part[512];  // [0..256)=kl partials, [256..512)=recon partials

__device__ __forceinline__ float b2f(uint16_t u) {
  union { uint32_t i; float f; } v; v.i = ((uint32_t)u) << 16; return v.f;
}
__device__ __forceinline__ uint16_t f2b(float f) {
  union { float f; uint32_t i; } v; v.f = f;
  uint32_t x = v.i;
  return (uint16_t)((x + 0x7fffu + ((x >> 16) & 1u)) >> 16);  // RNE
}

__device__ __forceinline__ void gload_lds16(const uint16_t* g, uint16_t* l) {
  __builtin_amdgcn_global_load_lds(
      (const __attribute__((address_space(1))) void*)g,
      (__attribute__((address_space(3))) void*)l, 16, 0, 0);
}

// convert 8 fp32 -> 8 bf16 (RNE), 16B store
__device__ __forceinline__ void cvt8(const float* s, uint16_t* d) {
  const f32x4 a = *(const f32x4*)s;
  const f32x4 b = *(const f32x4*)(s + 4);
  u16x8 o;
  o[0]=f2b(a[0]); o[1]=f2b(a[1]); o[2]=f2b(a[2]); o[3]=f2b(a[3]);
  o[4]=f2b(b[0]); o[5]=f2b(b[1]); o[6]=f2b(b[2]); o[7]=f2b(b[3]);
  *(u16x8*)d = o;
}

__global__ __launch_bounds__(256) void cvt_x_kernel(
    const float* __restrict__ src, uint16_t* __restrict__ dst)
{
  const int i = blockIdx.x * 256 + threadIdx.x;
  cvt8(src + (size_t)i * 8, dst + (size_t)i * 8);
}

// weights, concatenated into Wbf: [enc_w 2M | dec_w1 1M | dec_w2 1M | cw1 64K | cw2 64K]
__global__ __launch_bounds__(256) void cvt_weights_kernel(
    const float* __restrict__ ew, const float* __restrict__ d1,
    const float* __restrict__ d2, const float* __restrict__ c1,
    const float* __restrict__ c2, uint16_t* __restrict__ out)
{
  const int i = blockIdx.x * 256 + threadIdx.x;  // elem8 idx, total 540672
  const float* src; uint16_t* dst; int off;
  if (i < 262144)      { src = ew; dst = out;           off = i; }
  else if (i < 393216) { src = d1; dst = out + 2097152; off = i - 262144; }
  else if (i < 524288) { src = d2; dst = out + 3145728; off = i - 393216; }
  else if (i < 532480) { src = c1; dst = out + 4194304; off = i - 524288; }
  else                 { src = c2; dst = out + 4259840; off = i - 532480; }
  cvt8(src + (size_t)off * 8, dst + (size_t)off * 8);
}

// ---------------------------------------------------------------------------
// GEMM: C[m,n] = sum_k A[m,k]*W[n,k] + bias[n]. A,W bf16; bias fp32; C bf16/f32.
// BK=64, global_load_lds width-16 staging with XOR chunk swizzle (round-8
// verified: SQ_LDS_BANK_CONFLICT=0).
// SPLIT: epilogue routes cols [0,1024)->C0, [1024,2048)->C1 (encoder).
// RECON: epilogue also accumulates sum((v - Xref)^2) into g_part (spread).
// ---------------------------------------------------------------------------
template<int BM, int BN, int WM, int WN, typename TC, bool SPLIT, bool RECON>
__global__ __launch_bounds__(256) void gemm_bt_kernel(
    const uint16_t* __restrict__ A, const uint16_t* __restrict__ Wm,
    const float* __restrict__ bias, TC* __restrict__ C0, TC* __restrict__ C1,
    const float* __restrict__ Xref,
    int K, int lda, int ldw, int ldc)
{
  constexpr int BK = 64;
  static_assert(WM * WN == 4, "4 waves");
  constexpr int MI = BM / (WM * 16);
  constexpr int NI = BN / (WN * 16);
  constexpr int AI = (BM * BK * 2) / 4096;
  constexpr int WI = (BN * BK * 2) / 4096;

  __shared__ __align__(16) uint16_t lds[BM * BK + BN * BK];
  uint16_t* As = lds;
  uint16_t* Ws = lds + BM * BK;

  const int tid  = threadIdx.x;
  const int wave = tid >> 6;
  const int lane = tid & 63;
  const int q    = lane >> 4;
  const int r16  = lane & 15;
  const int wm   = wave / WN;
  const int wn   = wave % WN;

  const int bm = blockIdx.x * BM;
  const int bn = blockIdx.y * BN;

  const int sr = tid >> 3;               // row within a 32-row issue
  const int pc = tid & 7;                // physical chunk slot (16B units)

  f32x4 acc[MI][NI] = {};

  for (int k0 = 0; k0 < K; k0 += BK) {
#pragma unroll
    for (int i = 0; i < AI; ++i) {
      const int r = i * 32 + sr;
      const int c = pc ^ (r & 7);
      const uint16_t* g = A + (size_t)(bm + r) * lda + k0 + c * 8;
      gload_lds16(g, (uint16_t*)((char*)As + i * 4096 + wave * 1024));
    }
#pragma unroll
    for (int i = 0; i < WI; ++i) {
      const int r = i * 32 + sr;
      const int c = pc ^ (r & 7);
      const uint16_t* g = Wm + (size_t)(bn + r) * ldw + k0 + c * 8;
      gload_lds16(g, (uint16_t*)((char*)Ws + i * 4096 + wave * 1024));
    }
    __syncthreads();

#pragma unroll
    for (int ks = 0; ks < 2; ++ks) {
      bf16x8 af[MI], wf[NI];
#pragma unroll
      for (int mi = 0; mi < MI; ++mi) {
        const int row = wm * (MI * 16) + mi * 16 + r16;
        const int c   = (ks * 4 + q) ^ (row & 7);
        af[mi] = *(const bf16x8*)(As + row * BK + c * 8);
      }
#pragma unroll
      for (int ni = 0; ni < NI; ++ni) {
        const int col = wn * (NI * 16) + ni * 16 + r16;
        const int c   = (ks * 4 + q) ^ (col & 7);
        wf[ni] = *(const bf16x8*)(Ws + col * BK + c * 8);
      }
#pragma unroll
      for (int mi = 0; mi < MI; ++mi)
#pragma unroll
        for (int ni = 0; ni < NI; ++ni)
          acc[mi][ni] = __builtin_amdgcn_mfma_f32_16x16x32_bf16(
              af[mi], wf[ni], acc[mi][ni], 0, 0, 0);
    }
    __syncthreads();
  }

  // Epilogue. C/D layout (m89/m91 verified): col = lane&15, row = (lane>>4)*4+reg.
  TC* Cq = C0;
  int cb = bn;
  if constexpr (SPLIT) {
    if (bn >= 1024) { Cq = C1; cb = bn - 1024; }
  }
  float rsum = 0.f;
#pragma unroll
  for (int ni = 0; ni < NI; ++ni) {
    const int loc = wn * (NI * 16) + ni * 16 + r16;
    const float bv = bias[bn + loc];
#pragma unroll
    for (int mi = 0; mi < MI; ++mi) {
      const int rbase = bm + wm * (MI * 16) + mi * 16 + q * 4;
#pragma unroll
      for (int r = 0; r < 4; ++r) {
        const float v = acc[mi][ni][r] + bv;
        if constexpr (sizeof(TC) == 2)
          Cq[(size_t)(rbase + r) * ldc + cb + loc] = f2b(v);
        else
          Cq[(size_t)(rbase + r) * ldc + cb + loc] = v;
        if constexpr (RECON) {
          const float dd = v - Xref[(size_t)(rbase + r) * ldc + cb + loc];
          rsum += dd * dd;
        }
      }
    }
  }
  if constexpr (RECON) {
#pragma unroll
    for (int m = 1; m < 64; m <<= 1) rsum += __shfl_xor(rsum, m);
    __shared__ float redR[4];
    if (lane == 0) redR[wave] = rsum;
    __syncthreads();
    if (tid == 0)
      atomicAdd(&g_part[256 + ((blockIdx.x * 8 + blockIdx.y) & 255)],
                redR[0] + redR[1] + redR[2] + redR[3]);
  }
}

// ---------------------------------------------------------------------------
// Fused concept transform: z_t = ReLU(LN(zc@cw1^T + cb1)) @ cw2^T + cb2.
// Block = (concept c, 128-token tile), in-place on z ([NTOK,1024] bf16).
// 4 waves; wave handles its own 32 rows (disjoint LDS regions -> 1 barrier).
// LN(64) per row in registers: row spread over 16 lanes x 4 frags; 16-lane
// shuffle reduce. C->A layout transform via swizzled LDS round-trip.
// ---------------------------------------------------------------------------
__global__ __launch_bounds__(256) void concept_fused_kernel(
    uint16_t* __restrict__ z, const uint16_t* __restrict__ c1b,
    const uint16_t* __restrict__ c2b, const float* __restrict__ cb1,
    const float* __restrict__ cg, const float* __restrict__ cbt,
    const float* __restrict__ cb2)
{
  __shared__ __align__(16) uint16_t Az[128 * 64];   // zc tile, then t tile
  __shared__ __align__(16) uint16_t W1s[64 * 64];
  __shared__ __align__(16) uint16_t W2s[64 * 64];

  const int tid  = threadIdx.x;
  const int wave = tid >> 6;
  const int lane = tid & 63;
  const int q    = lane >> 4;
  const int r16  = lane & 15;
  const int c    = blockIdx.y;
  const int m0   = blockIdx.x * 128;

  const int lr = tid >> 3;
  const int pc = tid & 7;

  // stage zc tile (4 issues) + W1 (2) + W2 (2), all XOR-swizzled
#pragma unroll
  for (int i = 0; i < 4; ++i) {
    const int r = i * 32 + lr;
    const int gc = pc ^ (r & 7);
    gload_lds16(z + (size_t)(m0 + r) * DIM + c * 64 + gc * 8,
                (uint16_t*)((char*)Az + i * 4096 + wave * 1024));
  }
#pragma unroll
  for (int i = 0; i < 2; ++i) {
    const int r = i * 32 + lr;
    const int gc = pc ^ (r & 7);
    gload_lds16(c1b + (size_t)c * 4096 + r * 64 + gc * 8,
                (uint16_t*)((char*)W1s + i * 4096 + wave * 1024));
    gload_lds16(c2b + (size_t)c * 4096 + r * 64 + gc * 8,
                (uint16_t*)((char*)W2s + i * 4096 + wave * 1024));
  }
  __syncthreads();

  // MFMA1: t = zc @ cw1^T  (wave: 32 rows x 64 cols, MI=2, NI=4, K=64)
  f32x4 acc[2][4] = {};
#pragma unroll
  for (int ks = 0; ks < 2; ++ks) {
    bf16x8 af[2], wf[4];
#pragma unroll
    for (int mi = 0; mi < 2; ++mi) {
      const int row = wave * 32 + mi * 16 + r16;
      af[mi] = *(const bf16x8*)(Az + row * 64 + ((ks * 4 + q) ^ (row & 7)) * 8);
    }
#pragma unroll
    for (int ni = 0; ni < 4; ++ni) {
      const int d = ni * 16 + r16;
      wf[ni] = *(const bf16x8*)(W1s + d * 64 + ((ks * 4 + q) ^ (d & 7)) * 8);
    }
#pragma unroll
    for (int mi = 0; mi < 2; ++mi)
#pragma unroll
      for (int ni = 0; ni < 4; ++ni)
        acc[mi][ni] = __builtin_amdgcn_mfma_f32_16x16x32_bf16(
            af[mi], wf[ni], acc[mi][ni], 0, 0, 0);
  }

  // bias + LN(64) + ReLU in registers; write t (bf16) back into Az (swizzled)
  float b1v[4], cgv[4], cbv[4], b2v[4];
#pragma unroll
  for (int ni = 0; ni < 4; ++ni) {
    const int cn = ni * 16 + r16;
    b1v[ni] = cb1[c * 64 + cn];
    cgv[ni] = cg[c * 64 + cn];
    cbv[ni] = cbt[c * 64 + cn];
    b2v[ni] = cb2[c * 64 + cn];
  }
#pragma unroll
  for (int mi = 0; mi < 2; ++mi) {
#pragma unroll
    for (int r = 0; r < 4; ++r) {
      float s1 = 0.f, s2 = 0.f;
#pragma unroll
      for (int ni = 0; ni < 4; ++ni) {
        const float v = acc[mi][ni][r] + b1v[ni];
        acc[mi][ni][r] = v;
        s1 += v; s2 += v * v;
      }
#pragma unroll
      for (int m = 1; m < 16; m <<= 1) {  // 16-lane reduce (q preserved)
        s1 += __shfl_xor(s1, m);
        s2 += __shfl_xor(s2, m);
      }
      const float mean = s1 * (1.f / 64.f);
      const float var  = s2 * (1.f / 64.f) - mean * mean;
      const float rs   = rsqrtf(var + 1e-5f);
      const int row = wave * 32 + mi * 16 + q * 4 + r;
#pragma unroll
      for (int ni = 0; ni < 4; ++ni) {
        const float y = fmaxf((acc[mi][ni][r] - mean) * rs * cgv[ni] + cbv[ni], 0.f);
        const int cn = ni * 16 + r16;
        Az[row * 64 + (((cn >> 3) ^ (row & 7)) * 8) + (cn & 7)] = f2b(y);
      }
    }
  }
  __syncthreads();  // safety: drain LDS writes before A-layout reads

  // MFMA2: zt = t @ cw2^T
  f32x4 acc2[2][4] = {};
#pragma unroll
  for (int ks = 0; ks < 2; ++ks) {
    bf16x8 af[2], wf[4];
#pragma unroll
    for (int mi = 0; mi < 2; ++mi) {
      const int row = wave * 32 + mi * 16 + r16;
      af[mi] = *(const bf16x8*)(Az + row * 64 + ((ks * 4 + q) ^ (row & 7)) * 8);
    }
#pragma unroll
    for (int ni = 0; ni < 4; ++ni) {
      const int d = ni * 16 + r16;
      wf[ni] = *(const bf16x8*)(W2s + d * 64 + ((ks * 4 + q) ^ (d & 7)) * 8);
    }
#pragma unroll
    for (int mi = 0; mi < 2; ++mi)
#pragma unroll
      for (int ni = 0; ni < 4; ++ni)
        acc2[mi][ni] = __builtin_amdgcn_mfma_f32_16x16x32_bf16(
            af[mi], wf[ni], acc2[mi][ni], 0, 0, 0);
  }

  // epilogue: z_t -> z (in place; block's region is disjoint from all others)
#pragma unroll
  for (int mi = 0; mi < 2; ++mi)
#pragma unroll
    for (int ni = 0; ni < 4; ++ni) {
      const int cn = ni * 16 + r16;
#pragma unroll
      for (int r = 0; r < 4; ++r) {
        const int row = wave * 32 + mi * 16 + q * 4 + r;
        z[(size_t)(m0 + row) * DIM + c * 64 + cn] = f2b(acc2[mi][ni][r] + b2v[ni]);
      }
    }
}

// ---------------------------------------------------------------------------
// Fused: encoder LN (stats over the 2048-wide [mu|lv] row) + KL partials
// (spread atomics) + causal transform. One block (256 thr) per token.
// ---------------------------------------------------------------------------
__global__ __launch_bounds__(256) void kl_causal_kernel(
    const uint16_t* __restrict__ lv, uint16_t* __restrict__ mu,
    const float* __restrict__ g, const float* __restrict__ b,
    const float* __restrict__ dag_w)
{
  __shared__ __align__(16) float zsh[1024];
  __shared__ float dg[256];
  __shared__ float red[8];
  __shared__ float red2[4];
  const int tid = threadIdx.x;
  const int tok = blockIdx.x;
  const int e0  = tid * 4;

  {  // dag matrix: tril(softplus(dag_w), -1)
    const int di = tid >> 4, dj = tid & 15;
    dg[tid] = (dj < di) ? log1pf(expf(dag_w[tid])) : 0.f;
  }

  const uint16_t* lvp = lv + (size_t)tok * 1024;
  uint16_t*       mup = mu + (size_t)tok * 1024;

  const u16x4 m4 = *(const u16x4*)(mup + e0);
  const u16x4 l4 = *(const u16x4*)(lvp + e0);
  float xm[4], xl[4];
  float s1 = 0.f, s2 = 0.f;
#pragma unroll
  for (int k = 0; k < 4; ++k) {
    xm[k] = b2f(m4[k]);
    xl[k] = b2f(l4[k]);
    s1 += xm[k] + xl[k];
    s2 += xm[k] * xm[k] + xl[k] * xl[k];
  }
#pragma unroll
  for (int m = 1; m < 64; m <<= 1) {
    s1 += __shfl_xor(s1, m);
    s2 += __shfl_xor(s2, m);
  }
  const int wave = tid >> 6, lane = tid & 63;
  if (lane == 0) { red[wave] = s1; red[4 + wave] = s2; }
  __syncthreads();
  s1 = red[0] + red[1] + red[2] + red[3];
  s2 = red[4] + red[5] + red[6] + red[7];
  const float mean = s1 * (1.f / 2048.f);
  const float var  = s2 * (1.f / 2048.f) - mean * mean;
  const float rs   = rsqrtf(var + 1e-5f);

  const f32x4 g4m = *(const f32x4*)(g + e0);
  const f32x4 b4m = *(const f32x4*)(b + e0);
  const f32x4 g4l = *(const f32x4*)(g + 1024 + e0);
  const f32x4 b4l = *(const f32x4*)(b + 1024 + e0);
  float kl = 0.f;
  f32x4 z;
#pragma unroll
  for (int k = 0; k < 4; ++k) {
    z[k] = (xm[k] - mean) * rs * g4m[k] + b4m[k];
    const float y = (xl[k] - mean) * rs * g4l[k] + b4l[k];
    kl += 1.f + y - z[k] * z[k] - expf(y);
  }
  *(f32x4*)(zsh + e0) = z;
#pragma unroll
  for (int m = 1; m < 64; m <<= 1) kl += __shfl_xor(kl, m);
  if (lane == 0) red2[wave] = kl;
  __syncthreads();  // covers zsh, dg, red2
  if (tid == 0)
    atomicAdd(&g_part[tok & 255], red2[0] + red2[1] + red2[2] + red2[3]);

  // causal: thread covers elems [e0, e0+4) -> concept i = e0>>6, dims d0..d0+3
  const int i  = e0 >> 6;
  const int d0 = e0 & 63;
  f32x4 s = *(const f32x4*)(zsh + e0);
  for (int j = 0; j < i; ++j) {
    const float w = dg[i * 16 + j];
    const f32x4 zj = *(const f32x4*)(zsh + j * 64 + d0);
    s[0] += w * zj[0]; s[1] += w * zj[1]; s[2] += w * zj[2]; s[3] += w * zj[3];
  }
  u16x4 o;
#pragma unroll
  for (int k = 0; k < 4; ++k) o[k] = f2b(s[k]);
  *(u16x4*)(mup + e0) = o;
}

// ---------------------------------------------------------------------------
// LayerNorm(1024) + ReLU, in-place on bf16 rows, one block (256 thr) per row.
// ---------------------------------------------------------------------------
__global__ __launch_bounds__(256) void ln_relu_kernel(
    uint16_t* __restrict__ data, const float* __restrict__ g,
    const float* __restrict__ b)
{
  const int tid = threadIdx.x;
  const int e0  = tid * 4;
  uint16_t* p = data + (size_t)blockIdx.x * 1024;

  const u16x4 v4 = *(const u16x4*)(p + e0);
  float x[4];
  float s1 = 0.f, s2 = 0.f;
#pragma unroll
  for (int k = 0; k < 4; ++k) {
    x[k] = b2f(v4[k]);
    s1 += x[k];
    s2 += x[k] * x[k];
  }
#pragma unroll
  for (int m = 1; m < 64; m <<= 1) {
    s1 += __shfl_xor(s1, m);
    s2 += __shfl_xor(s2, m);
  }
  __shared__ float red[8];
  const int wave = tid >> 6, lane = tid & 63;
  if (lane == 0) { red[wave] = s1; red[4 + wave] = s2; }
  __syncthreads();
  s1 = red[0] + red[1] + red[2] + red[3];
  s2 = red[4] + red[5] + red[6] + red[7];
  const float mean = s1 * (1.f / 1024.f);
  const float var  = s2 * (1.f / 1024.f) - mean * mean;
  const float rs   = rsqrtf(var + 1e-5f);

  const f32x4 g4 = *(const f32x4*)(g + e0);
  const f32x4 b4 = *(const f32x4*)(b + e0);
  u16x4 o;
#pragma unroll
  for (int k = 0; k < 4; ++k) {
    const float y = (x[k] - mean) * rs * g4[k] + b4[k];
    o[k] = f2b(fmaxf(y, 0.f));
  }
  *(u16x4*)(p + e0) = o;
}

// ---------------------------------------------------------------------------
// init: zero 512 partial slots; dag_loss = sum(tril softplus) + 16.
// ---------------------------------------------------------------------------
__global__ __launch_bounds__(256) void dag_init_kernel(
    const float* __restrict__ dag_w)
{
  const int t = threadIdx.x;
  g_part[t] = 0.f;
  g_part[256 + t] = 0.f;
  const int i = t >> 4, j = t & 15;
  const float v = (j < i) ? log1pf(expf(dag_w[t])) : 0.f;
  float s = v;
#pragma unroll
  for (int m = 1; m < 64; m <<= 1) s += __shfl_xor(s, m);
  __shared__ float red[4];
  const int wave = t >> 6, lane = t & 63;
  if (lane == 0) red[wave] = s;
  __syncthreads();
  if (t == 0)
    g_scal[2] = red[0] + red[1] + red[2] + red[3] + 16.f;  // trace(expm)=C exactly
}

// ---------------------------------------------------------------------------
// finalize: sum the 256+256 partial slots, emit the 4 loss scalars.
// ---------------------------------------------------------------------------
__global__ __launch_bounds__(256) void finalize_kernel(float* __restrict__ out_tail)
{
  const int tid = threadIdx.x;
  float kl = g_part[tid];
  float rc = g_part[256 + tid];
#pragma unroll
  for (int m = 1; m < 64; m <<= 1) {
    kl += __shfl_xor(kl, m);
    rc += __shfl_xor(rc, m);
  }
  __shared__ float red[8];
  const int wave = tid >> 6, lane = tid & 63;
  if (lane == 0) { red[wave] = kl; red[4 + wave] = rc; }
  __syncthreads();
  if (tid == 0) {
    const float kls = red[0] + red[1] + red[2] + red[3];
    const float rcs = red[4] + red[5] + red[6] + red[7];
    const float kl_l   = -0.5f * kls * (1.f / (16384.f * 1024.f));
    const float recon  = rcs * (1.f / 16777216.f);
    const float dagl   = g_scal[2];
    out_tail[0] = recon + 0.3f * kl_l + 1.0f * dagl;
    out_tail[1] = kl_l;
    out_tail[2] = recon;
    out_tail[3] = dagl;
  }
}

// ---------------------------------------------------------------------------
extern "C" void kernel_launch(void* const* d_in, const int* in_sizes, int n_in,
                              void* d_out, int out_size, void* d_ws, size_t ws_size,
                              hipStream_t stream) {
  const float* x      = (const float*)d_in[0];
  const float* enc_w  = (const float*)d_in[1];
  const float* enc_b  = (const float*)d_in[2];
  const float* enc_g  = (const float*)d_in[3];
  const float* enc_bt = (const float*)d_in[4];
  const float* dag_w  = (const float*)d_in[5];
  const float* cw1    = (const float*)d_in[6];
  const float* cb1    = (const float*)d_in[7];
  const float* cg     = (const float*)d_in[8];
  const float* cbt    = (const float*)d_in[9];
  const float* cw2    = (const float*)d_in[10];
  const float* cb2    = (const float*)d_in[11];
  const float* dec_w1 = (const float*)d_in[12];
  const float* dec_b1 = (const float*)d_in[13];
  const float* dec_g  = (const float*)d_in[14];
  const float* dec_bt = (const float*)d_in[15];
  const float* dec_w2 = (const float*)d_in[16];
  const float* dec_b2 = (const float*)d_in[17];

  uint16_t* S    = (uint16_t*)d_ws;                       // [16384x1024] bf16, 32 MiB
  uint16_t* Wbf  = (uint16_t*)((char*)d_ws + (size_t)NTOK * DIM * 2);
  uint16_t* ewb  = Wbf;                                   // enc_w   2,097,152
  uint16_t* d1b  = Wbf + 2097152;                         // dec_w1  1,048,576
  uint16_t* d2b  = Wbf + 3145728;                         // dec_w2  1,048,576
  uint16_t* c1b  = Wbf + 4194304;                         // cw1       65,536
  uint16_t* c2b  = Wbf + 4259840;                         // cw2       65,536

  uint16_t* Obf  = (uint16_t*)d_out;                      // bf16 scratch (lower half)
  uint16_t* xbf  = Obf + (size_t)NOUT_ELEMS;              // x_bf16 (upper half)
  float*    O    = (float*)d_out;                         // final fp32 x_recon + losses

  // 1. zero partials + dag_loss
  dag_init_kernel<<<1, 256, 0, stream>>>(dag_w);

  // 1b. convert x and all weights to bf16
  cvt_x_kernel<<<NOUT_ELEMS / 8 / 256, 256, 0, stream>>>(x, xbf);
  cvt_weights_kernel<<<2112, 256, 0, stream>>>(enc_w, dec_w1, dec_w2, cw1, cw2, Wbf);

  // 2. encoder GEMM (merged, N=2048, split epilogue): mu -> Obf, lv -> S
  gemm_bt_kernel<128, 128, 2, 2, uint16_t, true, false>
      <<<dim3(128, 16, 1), 256, 0, stream>>>(
      xbf, ewb, enc_b, Obf, S, nullptr, DIM, DIM, DIM, DIM);

  // 3. fused LN + KL + causal: z_causal overwrites mu in Obf (xbf now dead)
  kl_causal_kernel<<<NTOK, 256, 0, stream>>>(S, Obf, enc_g, enc_bt, dag_w);

  // 4. fused concept transform (concept1 + LN64 + ReLU + concept2), in-place
  concept_fused_kernel<<<dim3(128, 16, 1), 256, 0, stream>>>(
      Obf, c1b, c2b, cb1, cg, cbt, cb2);

  // 5. decoder GEMM1: d_pre = z_t @ dec_w1^T + dec_b1 -> S
  gemm_bt_kernel<128, 128, 2, 2, uint16_t, false, false>
      <<<dim3(128, 8, 1), 256, 0, stream>>>(
      Obf, d1b, dec_b1, S, S, nullptr, DIM, DIM, DIM, DIM);

  // 6. decoder LN + ReLU (in-place on S)
  ln_relu_kernel<<<NTOK, 256, 0, stream>>>(S, dec_g, dec_bt);

  // 7. decoder GEMM2 + fused recon: x_recon = d @ dec_w2^T + dec_b2 -> O (fp32)
  gemm_bt_kernel<128, 128, 2, 2, float, false, true>
      <<<dim3(128, 8, 1), 256, 0, stream>>>(
      S, d2b, dec_b2, O, O, x, DIM, DIM, DIM, DIM);

  // 8. final scalars
  finalize_kernel<<<1, 256, 0, stream>>>(O + (size_t)NOUT_ELEMS);
}